// Round 7
// baseline (2862.466 us; speedup 1.0000x reference)
//
#include <hip/hip_runtime.h>
#include <hip/hip_bf16.h>
#include <math.h>

#define LDAB 1344  // A_perm col stride (1233 -> 1344)
#define LDR  1344  // hT row capacity
#define LDH  512   // padded G (500 -> 512)
#define LDX  320   // padded H (300 -> 320)

typedef __attribute__((ext_vector_type(8))) short short8;
typedef __attribute__((ext_vector_type(4))) float f32x4;
typedef unsigned short us;

__device__ __forceinline__ us f2b(float x){
    unsigned int u = __float_as_uint(x);
    return (us)((u + 0x7fffu + ((u >> 16) & 1u)) >> 16);
}
__device__ __forceinline__ float b2f(us u){ return __uint_as_float(((unsigned int)u) << 16); }

__device__ __forceinline__ float arc_sim(float c){
    float cc = fminf(1.f, fmaxf(-1.f, c * 0.99999f));
    return 1.f - acosf(cc) * 0.31830988618379067f;
}

// ---------------- offsets / permutation map / tile bands ----------------
__global__ void k_offsets(const int* __restrict__ dia, int N,
                          int* __restrict__ off13, int* __restrict__ rmap3, int* __restrict__ tileK)
{
    __shared__ int soff[13], slen[12];
    if (threadIdx.x == 0){
        int d = 0; soff[0] = 0;
        for (int i = 0; i < N; ++i){
            while (dia[i] > d){ ++d; soff[d] = i; }
        }
        for (int dd = d+1; dd <= 12; ++dd) soff[dd] = N;
        for (int dd = 0; dd < 12; ++dd) slen[dd] = soff[dd+1] - soff[dd];
        for (int dd = 0; dd < 13; ++dd) off13[dd] = soff[dd];
    }
    __syncthreads();
    for (int i = threadIdx.x; i < N; i += 64){
        int d = dia[i];
        int base = 3*soff[d], u = i - soff[d], l = slen[d];
        rmap3[0*448 + i] = base + u;
        rmap3[1*448 + i] = base + l + u;
        rmap3[2*448 + i] = base + 2*l + u;
    }
    if (threadIdx.x < 20){
        int it = threadIdx.x;
        int r0 = it*64, r1 = min(it*64 + 63, 3*N - 1);
        int dfirst = 11, dlast = 11;
        for (int dd = 0; dd < 12; ++dd){ if (r0 < 3*soff[dd+1]){ dfirst = dd; break; } }
        for (int dd = 0; dd < 12; ++dd){ if (r1 < 3*soff[dd+1]){ dlast = dd; break; } }
        tileK[it]      = (3*soff[dfirst]) & ~63;       // floored to 64 for aligned K-steps
        tileK[20 + it] = 3*soff[dlast] + 3*slen[dlast];
    }
}

// ---------------- gather ragged utterances into padded buffers + speaker idx ----------------
__global__ __launch_bounds__(256)
void k_gather(const float* __restrict__ fa, const float* __restrict__ fv, const float* __restrict__ ft,
              const float* __restrict__ speaker, const int* __restrict__ seq, const int* __restrict__ bat,
              float* __restrict__ xga, float* __restrict__ xgv, float* __restrict__ xgt,
              int* __restrict__ spki, int N)
{
    int i = blockIdx.x;
    int tid = threadIdx.x;
    bool real = i < N;
    int s = real ? seq[i] : 0, b = real ? bat[i] : 0;
    size_t base = (size_t)(s*12 + b);
    for (int k = tid; k < 1600; k += 256) xga[(size_t)i*1600 + k] = (real && k < 1582) ? fa[base*1582 + k] : 0.f;
    for (int k = tid; k < 384;  k += 256) xgv[(size_t)i*384  + k] = (real && k < 342)  ? fv[base*342  + k] : 0.f;
    for (int k = tid; k < 1024; k += 256) xgt[(size_t)i*1024 + k] = real ? ft[base*1024 + k] : 0.f;
    if (tid == 0){
        int bi = 0;
        if (real){
            const float* sp = speaker + base*9;
            float best = sp[0];
            for (int c = 1; c < 9; ++c) if (sp[c] > best){ best = sp[c]; bi = c; }
        }
        spki[i] = bi;
    }
}

// ---------------- transpose projection weight W[D][300] -> WT[300][Kp] fp32 ----------------
__global__ __launch_bounds__(256)
void k_trw(const float* __restrict__ W, int D, int Kp, float* __restrict__ WTr)
{
    __shared__ float tt[64][65];
    int k0 = blockIdx.x*64, j0 = blockIdx.y*64;
    int t = threadIdx.x;
    #pragma unroll
    for (int rr = 0; rr < 4; ++rr){
        int kl = (t >> 4) + rr*16;
        int k  = k0 + kl;
        int jl = (t & 15) * 4;
        int j  = j0 + jl;
        float4 v;
        if (k < D && j + 3 < 300){
            v = *(const float4*)&W[(size_t)k*300 + j];
        } else {
            v.x = (k < D && j+0 < 300) ? W[(size_t)k*300 + j+0] : 0.f;
            v.y = (k < D && j+1 < 300) ? W[(size_t)k*300 + j+1] : 0.f;
            v.z = (k < D && j+2 < 300) ? W[(size_t)k*300 + j+2] : 0.f;
            v.w = (k < D && j+3 < 300) ? W[(size_t)k*300 + j+3] : 0.f;
        }
        tt[jl+0][kl] = v.x; tt[jl+1][kl] = v.y; tt[jl+2][kl] = v.z; tt[jl+3][kl] = v.w;
    }
    __syncthreads();
    #pragma unroll
    for (int rr = 0; rr < 4; ++rr){
        int jl = (t >> 4) + rr*16;
        int j  = j0 + jl;
        int kq = (t & 15) * 4;
        if (j < 300){
            float4 o; o.x = tt[jl][kq]; o.y = tt[jl][kq+1]; o.z = tt[jl][kq+2]; o.w = tt[jl][kq+3];
            *(float4*)&WTr[(size_t)j*Kp + k0 + kq] = o;
        }
    }
}

// ---------------- projection GEMM partials (split-K) ----------------
__global__ __launch_bounds__(256)
void k_projg2(const float* __restrict__ xg, int Kp, int kslice,
              const float* __restrict__ WTr, float* __restrict__ xp)
{
    __shared__ float As[16][68];
    __shared__ float Bs[16][64];
    int i0 = blockIdx.y*64, j0 = blockIdx.x*64;
    int ks0 = blockIdx.z * kslice;
    int tid = threadIdx.x;
    int ty = tid >> 4, tx = tid & 15;
    int lr = tid >> 2, lk = (tid & 3) << 2;
    int bj = tid & 63, bk4 = (tid >> 6) << 2;
    float acc[4][4] = {};
    for (int k0 = 0; k0 < kslice; k0 += 16){
        float4 av = *(const float4*)&xg[(size_t)(i0+lr)*Kp + ks0 + k0 + lk];
        float4 wv = {0.f, 0.f, 0.f, 0.f};
        int j = j0 + bj;
        if (j < 300) wv = *(const float4*)&WTr[(size_t)j*Kp + ks0 + k0 + bk4];
        __syncthreads();
        As[lk+0][lr] = av.x; As[lk+1][lr] = av.y; As[lk+2][lr] = av.z; As[lk+3][lr] = av.w;
        Bs[bk4+0][bj] = wv.x; Bs[bk4+1][bj] = wv.y; Bs[bk4+2][bj] = wv.z; Bs[bk4+3][bj] = wv.w;
        __syncthreads();
        #pragma unroll
        for (int kk = 0; kk < 16; ++kk){
            float4 a4 = *(const float4*)&As[kk][ty*4];
            float4 b4 = *(const float4*)&Bs[kk][tx*4];
            float a_[4] = {a4.x, a4.y, a4.z, a4.w};
            float b_[4] = {b4.x, b4.y, b4.z, b4.w};
            #pragma unroll
            for (int u = 0; u < 4; ++u)
                #pragma unroll
                for (int v = 0; v < 4; ++v) acc[u][v] += a_[u]*b_[v];
        }
    }
    #pragma unroll
    for (int u = 0; u < 4; ++u){
        int i = i0 + ty*4 + u;
        #pragma unroll
        for (int v = 0; v < 4; ++v)
            xp[((size_t)blockIdx.z*448 + i)*320 + j0 + tx*4 + v] = acc[u][v];
    }
}

// ---------------- reduce split-K + bias + spk -> x (PERMUTED rows) and fn ----------------
__global__ __launch_bounds__(256)
void k_norm2(const float* __restrict__ xpa, const float* __restrict__ xpv, const float* __restrict__ xpt,
             const float* __restrict__ ba, const float* __restrict__ bv, const float* __restrict__ bt,
             const float* __restrict__ spk_emb, const int* __restrict__ spki,
             const int* __restrict__ rmap3,
             float* __restrict__ x, float* __restrict__ fn, int N)
{
    __shared__ float red[4];
    int r = blockIdx.x, tid = threadIdx.x;
    int m = (r >= 2*N) ? 2 : (r >= N ? 1 : 0);
    int n = r - m*N;
    const float* xp   = (m==0) ? xpa : (m==1) ? xpv : xpt;
    const float* bias = (m==0) ? ba  : (m==1) ? bv  : bt;
    int KS = (m==1) ? 2 : 4;
    float v0 = 0.f, v1 = 0.f;
    int j0 = tid, j1 = tid + 256;
    if (j0 < 300){
        float s = bias[j0];
        for (int si = 0; si < KS; ++si) s += xp[((size_t)si*448 + n)*320 + j0];
        if (m == 2) s += spk_emb[spki[n]*300 + j0];
        v0 = s;
    }
    if (j1 < 300){
        float s = bias[j1];
        for (int si = 0; si < KS; ++si) s += xp[((size_t)si*448 + n)*320 + j1];
        if (m == 2) s += spk_emb[spki[n]*300 + j1];
        v1 = s;
    }
    float ss = v0*v0 + v1*v1;
    #pragma unroll
    for (int off = 32; off > 0; off >>= 1) ss += __shfl_down(ss, off, 64);
    if ((tid & 63) == 0) red[tid >> 6] = ss;
    __syncthreads();
    float tot = red[0] + red[1] + red[2] + red[3];
    float inv = 1.f / (sqrtf(tot) + 1e-8f);
    int prow = rmap3[m*448 + n];
    x [(size_t)prow*LDX + j0] = v0;
    fn[(size_t)r*LDX + j0] = v0 * inv;
    if (j1 < 320){
        x [(size_t)prow*LDX + j1] = v1;
        fn[(size_t)r*LDX + j1] = v1 * inv;
    }
}

// ---------------- intra-modal adjacency -> PERMUTED block-diagonal A ----------------
__global__ __launch_bounds__(256)
void k_intra(const float* __restrict__ fn, const int* __restrict__ dia,
             const int* __restrict__ rmap3, float* __restrict__ A, int N)
{
    int m  = blockIdx.z;
    int i0 = blockIdx.y * 32, j0 = blockIdx.x * 32;
    int iend = min(i0 + 31, N - 1), jend = min(j0 + 31, N - 1);
    if (dia[iend] < dia[j0] || dia[jend] < dia[i0]) return;

    __shared__ float As[32][17], Bs[32][17];
    int tx = threadIdx.x, ty = threadIdx.y;
    int tid = ty*16 + tx;
    float acc[2][2] = {};
    for (int k0 = 0; k0 < 320; k0 += 16){
        __syncthreads();
        for (int l = tid; l < 512; l += 256){
            int r = l >> 4, kk = l & 15;
            int gi = i0 + r, gj = j0 + r;
            As[r][kk] = (gi < N) ? fn[((size_t)m*N + gi)*LDX + k0 + kk] : 0.f;
            Bs[r][kk] = (gj < N) ? fn[((size_t)m*N + gj)*LDX + k0 + kk] : 0.f;
        }
        __syncthreads();
        #pragma unroll
        for (int kk = 0; kk < 16; ++kk){
            float a0 = As[ty*2+0][kk], a1 = As[ty*2+1][kk];
            float b0 = Bs[tx*2+0][kk], b1 = Bs[tx*2+1][kk];
            acc[0][0] += a0*b0; acc[0][1] += a0*b1;
            acc[1][0] += a1*b0; acc[1][1] += a1*b1;
        }
    }
    #pragma unroll
    for (int u = 0; u < 2; ++u)
        #pragma unroll
        for (int v = 0; v < 2; ++v){
            int i = i0 + ty*2 + u, j = j0 + tx*2 + v;
            if (i < N && j < N && dia[i] == dia[j]){
                int pi = rmap3[m*448 + i], pj = rmap3[m*448 + j];
                A[(size_t)pi*LDAB + pj] = arc_sim(acc[u][v]);
            }
        }
}

// ---------------- cross-modal diagonal links (permuted) ----------------
__global__ void k_cross(const float* __restrict__ fn, const int* __restrict__ rmap3,
                        float* __restrict__ A, int N)
{
    int i = blockIdx.x, lane = threadIdx.x;
    float d01 = 0.f, d02 = 0.f, d12 = 0.f;
    for (int k = lane; k < 300; k += 64){
        float a = fn[((size_t)0*N + i)*LDX + k];
        float b = fn[((size_t)1*N + i)*LDX + k];
        float c = fn[((size_t)2*N + i)*LDX + k];
        d01 += a*b; d02 += a*c; d12 += b*c;
    }
    #pragma unroll
    for (int off = 32; off > 0; off >>= 1){
        d01 += __shfl_down(d01, off, 64);
        d02 += __shfl_down(d02, off, 64);
        d12 += __shfl_down(d12, off, 64);
    }
    if (lane == 0){
        float s01 = arc_sim(d01), s02 = arc_sim(d02), s12 = arc_sim(d12);
        size_t p0 = rmap3[i], p1 = rmap3[448 + i], p2 = rmap3[896 + i];
        A[p0*LDAB + p1] = s01; A[p1*LDAB + p0] = s01;
        A[p0*LDAB + p2] = s02; A[p2*LDAB + p0] = s02;
        A[p1*LDAB + p2] = s12; A[p2*LDAB + p1] = s12;
    }
}

// ---------------- degree + D^-1/2 ----------------
__global__ __launch_bounds__(256)
void k_rowsum(const float* __restrict__ A, float* __restrict__ dinv, int M3)
{
    __shared__ float red[4];
    int r = blockIdx.x, tid = threadIdx.x;
    float s = 0.f;
    for (int c = tid; c < LDAB; c += 256) s += A[(size_t)r*LDAB + c];
    #pragma unroll
    for (int off = 32; off > 0; off >>= 1) s += __shfl_down(s, off, 64);
    if ((tid & 63) == 0) red[tid >> 6] = s;
    __syncthreads();
    if (tid == 0){
        float tot = red[0] + red[1] + red[2] + red[3];
        dinv[r] = (tot > 0.f) ? 1.f / sqrtf(tot) : 0.f;
    }
}

// ---------------- scale + bf16 copy ----------------
__global__ void k_scale(float* __restrict__ A, us* __restrict__ Abf,
                        const float* __restrict__ dinv, int M3)
{
    int c = blockIdx.x*16 + threadIdx.x;
    int r = blockIdx.y*16 + threadIdx.y;
    if (r < M3 && c < M3){
        float v = A[(size_t)r*LDAB + c] * dinv[r]*dinv[c];
        A[(size_t)r*LDAB + c] = v;
        Abf[(size_t)r*LDAB + c] = f2b(v);
    }
}

// ---------------- h0 = relu(x @ W_in + b_in) (permuted rows) ----------------
__global__ __launch_bounds__(256)
void k_gemm_h0(const float* __restrict__ x, const float* __restrict__ Win,
               const float* __restrict__ bin, float* __restrict__ h0,
               us* __restrict__ h0b, us* __restrict__ h0bT, int M3)
{
    __shared__ float As[16][68];
    __shared__ float Bs[16][64];
    int i0 = blockIdx.y*64, j0 = blockIdx.x*64;
    int tid = threadIdx.x;
    int ty = tid >> 4, tx = tid & 15;
    int lr = tid >> 2, lk = (tid & 3) << 2;
    int br = tid >> 4, bc = (tid & 15) << 2;
    float acc[4][4] = {};
    for (int k0 = 0; k0 < 320; k0 += 16){
        float4 av = *(const float4*)&x[(size_t)(i0+lr)*LDX + k0 + lk];
        float4 bwv;
        {
            int kr = k0 + br;
            int c0 = j0 + bc;
            if (kr < 300 && c0 + 3 < 500){
                bwv = *(const float4*)&Win[(size_t)kr*500 + c0];
            } else {
                bwv.x = (kr < 300 && c0+0 < 500) ? Win[(size_t)kr*500 + c0+0] : 0.f;
                bwv.y = (kr < 300 && c0+1 < 500) ? Win[(size_t)kr*500 + c0+1] : 0.f;
                bwv.z = (kr < 300 && c0+2 < 500) ? Win[(size_t)kr*500 + c0+2] : 0.f;
                bwv.w = (kr < 300 && c0+3 < 500) ? Win[(size_t)kr*500 + c0+3] : 0.f;
            }
        }
        __syncthreads();
        As[lk+0][lr] = av.x; As[lk+1][lr] = av.y; As[lk+2][lr] = av.z; As[lk+3][lr] = av.w;
        *(float4*)&Bs[br][bc] = bwv;
        __syncthreads();
        #pragma unroll
        for (int kk = 0; kk < 16; ++kk){
            float4 a4 = *(const float4*)&As[kk][ty*4];
            float4 b4 = *(const float4*)&Bs[kk][tx*4];
            float a_[4] = {a4.x, a4.y, a4.z, a4.w};
            float b_[4] = {b4.x, b4.y, b4.z, b4.w};
            #pragma unroll
            for (int u = 0; u < 4; ++u)
                #pragma unroll
                for (int v = 0; v < 4; ++v) acc[u][v] += a_[u]*b_[v];
        }
    }
    #pragma unroll
    for (int u = 0; u < 4; ++u){
        int i = i0 + ty*4 + u;
        #pragma unroll
        for (int v = 0; v < 4; ++v){
            int j = j0 + tx*4 + v;
            float val = 0.f;
            if (i < M3 && j < 500) val = fmaxf(acc[u][v] + bin[j], 0.f);
            h0[(size_t)i*LDH + j] = val;
            us bv = f2b(val);
            h0b[(size_t)i*LDH + j] = bv;
            h0bT[(size_t)j*LDR + i] = bv;
        }
    }
}

// ---------------- convert ALL 64 layers of W to bf16 transposed ----------------
__global__ __launch_bounds__(256)
void k_wtr(const float* __restrict__ Wc, us* __restrict__ Wt)
{
    __shared__ us sT[64][72];
    int l = blockIdx.z;
    int k0 = blockIdx.x*64, j0 = blockIdx.y*64;
    const float* W = Wc + (size_t)l*500000;
    int ksrc0 = (k0 < 512) ? k0 : k0 - 12;
    int klim  = (k0 < 512) ? 500 : 1000;
    int t = threadIdx.x;
    #pragma unroll
    for (int rr = 0; rr < 4; ++rr){
        int kl = (t >> 4) + rr*16;
        int k  = ksrc0 + kl;
        int jl = (t & 15) * 4;
        int j  = j0 + jl;
        bool vk = (k < klim);
        float4 v;
        if (vk && j + 3 < 500){
            v = *(const float4*)&W[(size_t)k*500 + j];
        } else {
            v.x = (vk && j+0 < 500) ? W[(size_t)k*500 + j+0] : 0.f;
            v.y = (vk && j+1 < 500) ? W[(size_t)k*500 + j+1] : 0.f;
            v.z = (vk && j+2 < 500) ? W[(size_t)k*500 + j+2] : 0.f;
            v.w = (vk && j+3 < 500) ? W[(size_t)k*500 + j+3] : 0.f;
        }
        sT[jl+0][kl] = f2b(v.x);
        sT[jl+1][kl] = f2b(v.y);
        sT[jl+2][kl] = f2b(v.z);
        sT[jl+3][kl] = f2b(v.w);
    }
    __syncthreads();
    int jl = t >> 2, kc = (t & 3) * 16;
    us* dst = Wt + (size_t)l*LDH*1024 + (size_t)(j0+jl)*1024 + k0 + kc;
    *(uint4*)&dst[0] = *(const uint4*)&sT[jl][kc];
    *(uint4*)&dst[8] = *(const uint4*)&sT[jl][kc+8];
}

// ---------------- per-layer fused kernel: slab GEMM1 (LDS) + GEMM2 + epilogue ----------------
// grid 160 = (it 20) x (jt 8); block 512 = 8 waves
__global__ __launch_bounds__(512)
void k_layer3(const us* __restrict__ Abf, const us* __restrict__ src,
              const float* __restrict__ h0, const us* __restrict__ h0b,
              const us* __restrict__ Wl, const int* __restrict__ tileK,
              float th, us* __restrict__ dst)
{
    __shared__ us    slabB[64][520];   // 66,560 B : hi slab bf16 (GEMM2 A-operand)
    __shared__ float sepF [64][68];    // 17,408 B : hi fp32 window (epilogue residual)

    const int tid = threadIdx.x, lane = tid & 63, w = tid >> 6;
    const int lm = lane & 15, lq = lane >> 4;
    const int bid = blockIdx.x;
    const int it = bid >> 3, jt = bid & 7;
    const int i0 = it*64, j0 = jt*64;
    const int kminf = tileK[it] & ~63;
    const int kmax  = tileK[20 + it];
    const int T = (kmax - kminf + 31) >> 5;    // 32-wide K steps

    // ===== GEMM1: full 64x512 hi slab for this i-tile, banded K =====
    f32x4 accS[4][4] = {};
    for (int t = 0; t < T; ++t){
        int kp = kminf + t*32 + lq*8;
        short8 af[4], bfv[4];
        #pragma unroll
        for (int fr = 0; fr < 4; ++fr)
            af[fr] = *(const short8*)&Abf[(size_t)(i0 + fr*16 + lm)*LDAB + kp];
        #pragma unroll
        for (int fc = 0; fc < 4; ++fc)
            bfv[fc] = *(const short8*)&src[(size_t)(w*64 + fc*16 + lm)*LDR + kp];
        #pragma unroll
        for (int fr = 0; fr < 4; ++fr)
            #pragma unroll
            for (int fc = 0; fc < 4; ++fc)
                accS[fr][fc] = __builtin_amdgcn_mfma_f32_16x16x32_bf16(af[fr], bfv[fc], accS[fr][fc], 0, 0, 0);
    }
    // write slab (bf16) + fp32 window for the jt column block
    #pragma unroll
    for (int fr = 0; fr < 4; ++fr)
        #pragma unroll
        for (int fc = 0; fc < 4; ++fc)
            #pragma unroll
            for (int rg = 0; rg < 4; ++rg){
                int row = fr*16 + lq*4 + rg;
                int col = w*64 + fc*16 + lm;
                float v = accS[fr][fc][rg];
                slabB[row][col] = f2b(v);
                if (w == jt) sepF[row][fc*16 + lm] = v;
            }
    __syncthreads();

    // ===== GEMM2: out tile 64x64 (K=1024: slab | h0b), W from global =====
    const int r16 = (w & 3) * 16, cb = (w >> 2) * 32;
    f32x4 accG[2] = {};
    for (int t = 0; t < 32; ++t){
        int kp = t*32 + lq*8;
        short8 a;
        if (kp < 512) a = *(const short8*)&slabB[r16 + lm][kp];
        else          a = *(const short8*)&h0b[(size_t)(i0 + r16 + lm)*LDH + kp - 512];
        #pragma unroll
        for (int fc = 0; fc < 2; ++fc){
            short8 b = *(const short8*)&Wl[(size_t)(j0 + cb + fc*16 + lm)*1024 + kp];
            accG[fc] = __builtin_amdgcn_mfma_f32_16x16x32_bf16(a, b, accG[fc], 0, 0, 0);
        }
    }

    // ===== epilogue: h_next = relu(th*GEMM2 + (1-th)*(0.9 hi + 0.1 h0)), write transposed =====
    float cth = 1.f - th;
    #pragma unroll
    for (int fc = 0; fc < 2; ++fc){
        unsigned int pk[2];
        unsigned int tmp0 = 0, tmp1 = 0;
        #pragma unroll
        for (int rg = 0; rg < 4; ++rg){
            int il = r16 + lq*4 + rg;
            int jl = cb + fc*16 + lm;
            float hiv = sepF[il][jl];
            float h0v = h0[(size_t)(i0 + il)*LDH + j0 + jl];
            float o = fmaxf(th*accG[fc][rg] + cth*(0.9f*hiv + 0.1f*h0v), 0.f);
            unsigned int ob = (unsigned int)f2b(o);
            if (rg < 2) tmp0 |= ob << (16*rg);
            else        tmp1 |= ob << (16*(rg-2));
        }
        pk[0] = tmp0; pk[1] = tmp1;
        int jg = j0 + cb + fc*16 + lm;
        int ig = i0 + r16 + lq*4;
        *(uint2*)&dst[(size_t)jg*LDR + ig] = *(uint2*)pk;
    }
}

// ---------------- final classify + log_softmax ----------------
__global__ void k_final(const us* __restrict__ hT, const float* __restrict__ Wfc,
                        const float* __restrict__ bfc, const int* __restrict__ rmap3,
                        float* __restrict__ out, int N)
{
    int i = blockIdx.x, lane = threadIdx.x;
    int p0 = rmap3[i], p1 = rmap3[448 + i], p2 = rmap3[896 + i];
    float acc[7] = {};
    for (int k = lane; k < 1500; k += 64){
        int m = (k >= 1000) ? 2 : ((k >= 500) ? 1 : 0);
        int kk = k - m*500;
        int prow = (m == 0) ? p0 : (m == 1) ? p1 : p2;
        float f = fmaxf(b2f(hT[(size_t)kk*LDR + prow]), 0.f);
        #pragma unroll
        for (int c = 0; c < 7; ++c) acc[c] += f * Wfc[(size_t)k*7 + c];
    }
    #pragma unroll
    for (int off = 32; off > 0; off >>= 1){
        #pragma unroll
        for (int c = 0; c < 7; ++c) acc[c] += __shfl_down(acc[c], off, 64);
    }
    if (lane == 0){
        float lg[7], mx = -1e30f;
        #pragma unroll
        for (int c = 0; c < 7; ++c){ lg[c] = acc[c] + bfc[c]; mx = fmaxf(mx, lg[c]); }
        float s = 0.f;
        #pragma unroll
        for (int c = 0; c < 7; ++c) s += expf(lg[c] - mx);
        float lse = mx + logf(s);
        #pragma unroll
        for (int c = 0; c < 7; ++c) out[(size_t)i*7 + c] = lg[c] - lse;
    }
}

extern "C" void kernel_launch(void* const* d_in, const int* in_sizes, int n_in,
                              void* d_out, int out_size, void* d_ws, size_t ws_size,
                              hipStream_t stream)
{
    const float* speaker = (const float*)d_in[1];
    const float* fea_a   = (const float*)d_in[2];
    const float* fea_v   = (const float*)d_in[3];
    const float* fea_t   = (const float*)d_in[4];
    const float* Wa      = (const float*)d_in[5];
    const float* ba      = (const float*)d_in[6];
    const float* Wv      = (const float*)d_in[7];
    const float* bv      = (const float*)d_in[8];
    const float* Wt_in   = (const float*)d_in[9];
    const float* bt      = (const float*)d_in[10];
    const float* spk_emb = (const float*)d_in[11];
    const float* W_in    = (const float*)d_in[12];
    const float* b_in    = (const float*)d_in[13];
    const float* W_convs = (const float*)d_in[14];
    const float* W_fc1   = (const float*)d_in[15];
    const float* b_fc1   = (const float*)d_in[16];
    const int* seq = (const int*)d_in[18];
    const int* bat = (const int*)d_in[19];
    const int* dia = (const int*)d_in[20];

    const int N  = in_sizes[18];   // 411
    const int M3 = 3*N;            // 1233

    char* wsb = (char*)d_ws;
    float* A     = (float*)(wsb + 0);             // 1344*1344*4 = 7,225,344
    us*    Abf   = (us*)   (wsb + 8388608);       // 3,612,672
    float* x     = (float*)(wsb + 12582912);
    float* fn    = (float*)(wsb + 14680064);
    float* h0    = (float*)(wsb + 16777216);
    us*    h0b   = (us*)   (wsb + 19922944);
    us*    h0bT  = (us*)   (wsb + 21495808);      // 512*1344*2
    us*    hTa   = (us*)   (wsb + 23068672);
    us*    hTb   = (us*)   (wsb + 24641536);
    us*    Wt    = (us*)   (wsb + 33554432);      // 64*512*1024*2 = 67,108,864
    float* dinv  = (float*)(wsb + 100663296);
    int*   off13 = (int*)  (wsb + 100669440);
    int*   rmap3 = (int*)  (wsb + 100670464);
    int*   tileK = (int*)  (wsb + 100676608);
    int*   spki  = (int*)  (wsb + 100853760);
    float* xga   = (float*)(wsb + 100859904);
    float* xgv   = (float*)(wsb + 103727104);
    float* xgt   = (float*)(wsb + 104415232);
    float* WaT   = (float*)(wsb + 106250240);
    float* WvT   = (float*)(wsb + 108170240);
    float* WtT   = (float*)(wsb + 108631040);
    float* xpa   = (float*)(wsb + 109859840);
    float* xpv   = (float*)(wsb + 112153600);
    float* xpt   = (float*)(wsb + 113300480);

    hipMemsetAsync(A,    0, 7225344, stream);
    hipMemsetAsync(Abf,  0, 3612672, stream);
    hipMemsetAsync(x,    0, 1638400, stream);
    hipMemsetAsync(fn,   0, 1638400, stream);
    hipMemsetAsync(h0bT, 0, 1376256, stream);
    hipMemsetAsync(hTa,  0, 1376256, stream);
    hipMemsetAsync(hTb,  0, 1376256, stream);

    k_offsets<<<1, 64, 0, stream>>>(dia, N, off13, rmap3, tileK);
    k_gather<<<448, 256, 0, stream>>>(fea_a, fea_v, fea_t, speaker, seq, bat, xga, xgv, xgt, spki, N);

    k_trw<<<dim3(25, 5), 256, 0, stream>>>(Wa,    1582, 1600, WaT);
    k_trw<<<dim3( 6, 5), 256, 0, stream>>>(Wv,     342,  384, WvT);
    k_trw<<<dim3(16, 5), 256, 0, stream>>>(Wt_in, 1024, 1024, WtT);

    k_projg2<<<dim3(5, 7, 4), 256, 0, stream>>>(xga, 1600, 400, WaT, xpa);
    k_projg2<<<dim3(5, 7, 2), 256, 0, stream>>>(xgv,  384, 192, WvT, xpv);
    k_projg2<<<dim3(5, 7, 4), 256, 0, stream>>>(xgt, 1024, 256, WtT, xpt);

    k_norm2<<<M3, 256, 0, stream>>>(xpa, xpv, xpt, ba, bv, bt, spk_emb, spki, rmap3, x, fn, N);

    int nt = (N + 31)/32;
    k_intra<<<dim3(nt, nt, 3), dim3(16,16), 0, stream>>>(fn, dia, rmap3, A, N);
    k_cross<<<N, 64, 0, stream>>>(fn, rmap3, A, N);
    k_rowsum<<<M3, 256, 0, stream>>>(A, dinv, M3);
    k_scale<<<dim3(78, 78), dim3(16,16), 0, stream>>>(A, Abf, dinv, M3);

    k_gemm_h0<<<dim3(8, 20), 256, 0, stream>>>(x, W_in, b_in, h0, h0b, h0bT, M3);
    k_wtr<<<dim3(16, 8, 64), 256, 0, stream>>>(W_convs, Wt);

    const us* srcp = h0bT;
    for (int l = 1; l <= 64; ++l){
        us* dstp = ((l-1) & 1) ? hTb : hTa;
        float thv = logf(0.5f/(float)l + 1.0f);
        k_layer3<<<160, 512, 0, stream>>>(Abf, srcp, h0, h0b,
                                          Wt + (size_t)(l-1)*LDH*1024, tileK, thv, dstp);
        srcp = dstp;
    }

    k_final<<<N, 64, 0, stream>>>(hTb, W_fc1, b_fc1, rmap3, (float*)d_out, N);
}

// Round 8
// 2613.136 us; speedup vs baseline: 1.0954x; 1.0954x over previous
//
#include <hip/hip_runtime.h>
#include <hip/hip_bf16.h>
#include <math.h>

#define LDAB 1344  // A_perm col stride (1233 -> 1344)
#define LDR  1344  // hT row capacity
#define LDH  512   // padded G (500 -> 512)
#define LDX  320   // padded H (300 -> 320)

typedef __attribute__((ext_vector_type(8))) short short8;
typedef __attribute__((ext_vector_type(4))) float f32x4;
typedef unsigned short us;

__device__ __forceinline__ us f2b(float x){
    unsigned int u = __float_as_uint(x);
    return (us)((u + 0x7fffu + ((u >> 16) & 1u)) >> 16);
}
__device__ __forceinline__ float b2f(us u){ return __uint_as_float(((unsigned int)u) << 16); }

__device__ __forceinline__ float arc_sim(float c){
    float cc = fminf(1.f, fmaxf(-1.f, c * 0.99999f));
    return 1.f - acosf(cc) * 0.31830988618379067f;
}

#define SWZ(r, k) (((r)*64 + (k)) ^ (((r)&7)<<3))

// ---------------- offsets / permutation map / tile bands ----------------
__global__ void k_offsets(const int* __restrict__ dia, int N,
                          int* __restrict__ off13, int* __restrict__ rmap3, int* __restrict__ tileK)
{
    __shared__ int soff[13], slen[12];
    if (threadIdx.x == 0){
        int d = 0; soff[0] = 0;
        for (int i = 0; i < N; ++i){
            while (dia[i] > d){ ++d; soff[d] = i; }
        }
        for (int dd = d+1; dd <= 12; ++dd) soff[dd] = N;
        for (int dd = 0; dd < 12; ++dd) slen[dd] = soff[dd+1] - soff[dd];
        for (int dd = 0; dd < 13; ++dd) off13[dd] = soff[dd];
    }
    __syncthreads();
    for (int i = threadIdx.x; i < N; i += 64){
        int d = dia[i];
        int base = 3*soff[d], u = i - soff[d], l = slen[d];
        rmap3[0*448 + i] = base + u;
        rmap3[1*448 + i] = base + l + u;
        rmap3[2*448 + i] = base + 2*l + u;
    }
    if (threadIdx.x < 20){
        int it = threadIdx.x;
        int r0 = it*64, r1 = min(it*64 + 63, 3*N - 1);
        int dfirst = 11, dlast = 11;
        for (int dd = 0; dd < 12; ++dd){ if (r0 < 3*soff[dd+1]){ dfirst = dd; break; } }
        for (int dd = 0; dd < 12; ++dd){ if (r1 < 3*soff[dd+1]){ dlast = dd; break; } }
        tileK[it]      = (3*soff[dfirst]) & ~63;       // floored to 64 for aligned K-steps
        tileK[20 + it] = 3*soff[dlast] + 3*slen[dlast];
    }
}

// ---------------- gather ragged utterances into padded buffers + speaker idx ----------------
__global__ __launch_bounds__(256)
void k_gather(const float* __restrict__ fa, const float* __restrict__ fv, const float* __restrict__ ft,
              const float* __restrict__ speaker, const int* __restrict__ seq, const int* __restrict__ bat,
              float* __restrict__ xga, float* __restrict__ xgv, float* __restrict__ xgt,
              int* __restrict__ spki, int N)
{
    int i = blockIdx.x;
    int tid = threadIdx.x;
    bool real = i < N;
    int s = real ? seq[i] : 0, b = real ? bat[i] : 0;
    size_t base = (size_t)(s*12 + b);
    for (int k = tid; k < 1600; k += 256) xga[(size_t)i*1600 + k] = (real && k < 1582) ? fa[base*1582 + k] : 0.f;
    for (int k = tid; k < 384;  k += 256) xgv[(size_t)i*384  + k] = (real && k < 342)  ? fv[base*342  + k] : 0.f;
    for (int k = tid; k < 1024; k += 256) xgt[(size_t)i*1024 + k] = real ? ft[base*1024 + k] : 0.f;
    if (tid == 0){
        int bi = 0;
        if (real){
            const float* sp = speaker + base*9;
            float best = sp[0];
            for (int c = 1; c < 9; ++c) if (sp[c] > best){ best = sp[c]; bi = c; }
        }
        spki[i] = bi;
    }
}

// ---------------- transpose projection weight W[D][300] -> WT[300][Kp] fp32 ----------------
__global__ __launch_bounds__(256)
void k_trw(const float* __restrict__ W, int D, int Kp, float* __restrict__ WTr)
{
    __shared__ float tt[64][65];
    int k0 = blockIdx.x*64, j0 = blockIdx.y*64;
    int t = threadIdx.x;
    #pragma unroll
    for (int rr = 0; rr < 4; ++rr){
        int kl = (t >> 4) + rr*16;
        int k  = k0 + kl;
        int jl = (t & 15) * 4;
        int j  = j0 + jl;
        float4 v;
        if (k < D && j + 3 < 300){
            v = *(const float4*)&W[(size_t)k*300 + j];
        } else {
            v.x = (k < D && j+0 < 300) ? W[(size_t)k*300 + j+0] : 0.f;
            v.y = (k < D && j+1 < 300) ? W[(size_t)k*300 + j+1] : 0.f;
            v.z = (k < D && j+2 < 300) ? W[(size_t)k*300 + j+2] : 0.f;
            v.w = (k < D && j+3 < 300) ? W[(size_t)k*300 + j+3] : 0.f;
        }
        tt[jl+0][kl] = v.x; tt[jl+1][kl] = v.y; tt[jl+2][kl] = v.z; tt[jl+3][kl] = v.w;
    }
    __syncthreads();
    #pragma unroll
    for (int rr = 0; rr < 4; ++rr){
        int jl = (t >> 4) + rr*16;
        int j  = j0 + jl;
        int kq = (t & 15) * 4;
        if (j < 300){
            float4 o; o.x = tt[jl][kq]; o.y = tt[jl][kq+1]; o.z = tt[jl][kq+2]; o.w = tt[jl][kq+3];
            *(float4*)&WTr[(size_t)j*Kp + k0 + kq] = o;
        }
    }
}

// ---------------- projection GEMM partials (split-K) ----------------
__global__ __launch_bounds__(256)
void k_projg2(const float* __restrict__ xg, int Kp, int kslice,
              const float* __restrict__ WTr, float* __restrict__ xp)
{
    __shared__ float As[16][68];
    __shared__ float Bs[16][64];
    int i0 = blockIdx.y*64, j0 = blockIdx.x*64;
    int ks0 = blockIdx.z * kslice;
    int tid = threadIdx.x;
    int ty = tid >> 4, tx = tid & 15;
    int lr = tid >> 2, lk = (tid & 3) << 2;
    int bj = tid & 63, bk4 = (tid >> 6) << 2;
    float acc[4][4] = {};
    for (int k0 = 0; k0 < kslice; k0 += 16){
        float4 av = *(const float4*)&xg[(size_t)(i0+lr)*Kp + ks0 + k0 + lk];
        float4 wv = {0.f, 0.f, 0.f, 0.f};
        int j = j0 + bj;
        if (j < 300) wv = *(const float4*)&WTr[(size_t)j*Kp + ks0 + k0 + bk4];
        __syncthreads();
        As[lk+0][lr] = av.x; As[lk+1][lr] = av.y; As[lk+2][lr] = av.z; As[lk+3][lr] = av.w;
        Bs[bk4+0][bj] = wv.x; Bs[bk4+1][bj] = wv.y; Bs[bk4+2][bj] = wv.z; Bs[bk4+3][bj] = wv.w;
        __syncthreads();
        #pragma unroll
        for (int kk = 0; kk < 16; ++kk){
            float4 a4 = *(const float4*)&As[kk][ty*4];
            float4 b4 = *(const float4*)&Bs[kk][tx*4];
            float a_[4] = {a4.x, a4.y, a4.z, a4.w};
            float b_[4] = {b4.x, b4.y, b4.z, b4.w};
            #pragma unroll
            for (int u = 0; u < 4; ++u)
                #pragma unroll
                for (int v = 0; v < 4; ++v) acc[u][v] += a_[u]*b_[v];
        }
    }
    #pragma unroll
    for (int u = 0; u < 4; ++u){
        int i = i0 + ty*4 + u;
        #pragma unroll
        for (int v = 0; v < 4; ++v)
            xp[((size_t)blockIdx.z*448 + i)*320 + j0 + tx*4 + v] = acc[u][v];
    }
}

// ---------------- reduce split-K + bias + spk -> x (PERMUTED rows) and fn ----------------
__global__ __launch_bounds__(256)
void k_norm2(const float* __restrict__ xpa, const float* __restrict__ xpv, const float* __restrict__ xpt,
             const float* __restrict__ ba, const float* __restrict__ bv, const float* __restrict__ bt,
             const float* __restrict__ spk_emb, const int* __restrict__ spki,
             const int* __restrict__ rmap3,
             float* __restrict__ x, float* __restrict__ fn, int N)
{
    __shared__ float red[4];
    int r = blockIdx.x, tid = threadIdx.x;
    int m = (r >= 2*N) ? 2 : (r >= N ? 1 : 0);
    int n = r - m*N;
    const float* xp   = (m==0) ? xpa : (m==1) ? xpv : xpt;
    const float* bias = (m==0) ? ba  : (m==1) ? bv  : bt;
    int KS = (m==1) ? 2 : 4;
    float v0 = 0.f, v1 = 0.f;
    int j0 = tid, j1 = tid + 256;
    if (j0 < 300){
        float s = bias[j0];
        for (int si = 0; si < KS; ++si) s += xp[((size_t)si*448 + n)*320 + j0];
        if (m == 2) s += spk_emb[spki[n]*300 + j0];
        v0 = s;
    }
    if (j1 < 300){
        float s = bias[j1];
        for (int si = 0; si < KS; ++si) s += xp[((size_t)si*448 + n)*320 + j1];
        if (m == 2) s += spk_emb[spki[n]*300 + j1];
        v1 = s;
    }
    float ss = v0*v0 + v1*v1;
    #pragma unroll
    for (int off = 32; off > 0; off >>= 1) ss += __shfl_down(ss, off, 64);
    if ((tid & 63) == 0) red[tid >> 6] = ss;
    __syncthreads();
    float tot = red[0] + red[1] + red[2] + red[3];
    float inv = 1.f / (sqrtf(tot) + 1e-8f);
    int prow = rmap3[m*448 + n];
    x [(size_t)prow*LDX + j0] = v0;
    fn[(size_t)r*LDX + j0] = v0 * inv;
    if (j1 < 320){
        x [(size_t)prow*LDX + j1] = v1;
        fn[(size_t)r*LDX + j1] = v1 * inv;
    }
}

// ---------------- intra-modal adjacency -> PERMUTED block-diagonal A ----------------
__global__ __launch_bounds__(256)
void k_intra(const float* __restrict__ fn, const int* __restrict__ dia,
             const int* __restrict__ rmap3, float* __restrict__ A, int N)
{
    int m  = blockIdx.z;
    int i0 = blockIdx.y * 32, j0 = blockIdx.x * 32;
    int iend = min(i0 + 31, N - 1), jend = min(j0 + 31, N - 1);
    if (dia[iend] < dia[j0] || dia[jend] < dia[i0]) return;

    __shared__ float As[32][17], Bs[32][17];
    int tx = threadIdx.x, ty = threadIdx.y;
    int tid = ty*16 + tx;
    float acc[2][2] = {};
    for (int k0 = 0; k0 < 320; k0 += 16){
        __syncthreads();
        for (int l = tid; l < 512; l += 256){
            int r = l >> 4, kk = l & 15;
            int gi = i0 + r, gj = j0 + r;
            As[r][kk] = (gi < N) ? fn[((size_t)m*N + gi)*LDX + k0 + kk] : 0.f;
            Bs[r][kk] = (gj < N) ? fn[((size_t)m*N + gj)*LDX + k0 + kk] : 0.f;
        }
        __syncthreads();
        #pragma unroll
        for (int kk = 0; kk < 16; ++kk){
            float a0 = As[ty*2+0][kk], a1 = As[ty*2+1][kk];
            float b0 = Bs[tx*2+0][kk], b1 = Bs[tx*2+1][kk];
            acc[0][0] += a0*b0; acc[0][1] += a0*b1;
            acc[1][0] += a1*b0; acc[1][1] += a1*b1;
        }
    }
    #pragma unroll
    for (int u = 0; u < 2; ++u)
        #pragma unroll
        for (int v = 0; v < 2; ++v){
            int i = i0 + ty*2 + u, j = j0 + tx*2 + v;
            if (i < N && j < N && dia[i] == dia[j]){
                int pi = rmap3[m*448 + i], pj = rmap3[m*448 + j];
                A[(size_t)pi*LDAB + pj] = arc_sim(acc[u][v]);
            }
        }
}

// ---------------- cross-modal diagonal links (permuted) ----------------
__global__ void k_cross(const float* __restrict__ fn, const int* __restrict__ rmap3,
                        float* __restrict__ A, int N)
{
    int i = blockIdx.x, lane = threadIdx.x;
    float d01 = 0.f, d02 = 0.f, d12 = 0.f;
    for (int k = lane; k < 300; k += 64){
        float a = fn[((size_t)0*N + i)*LDX + k];
        float b = fn[((size_t)1*N + i)*LDX + k];
        float c = fn[((size_t)2*N + i)*LDX + k];
        d01 += a*b; d02 += a*c; d12 += b*c;
    }
    #pragma unroll
    for (int off = 32; off > 0; off >>= 1){
        d01 += __shfl_down(d01, off, 64);
        d02 += __shfl_down(d02, off, 64);
        d12 += __shfl_down(d12, off, 64);
    }
    if (lane == 0){
        float s01 = arc_sim(d01), s02 = arc_sim(d02), s12 = arc_sim(d12);
        size_t p0 = rmap3[i], p1 = rmap3[448 + i], p2 = rmap3[896 + i];
        A[p0*LDAB + p1] = s01; A[p1*LDAB + p0] = s01;
        A[p0*LDAB + p2] = s02; A[p2*LDAB + p0] = s02;
        A[p1*LDAB + p2] = s12; A[p2*LDAB + p1] = s12;
    }
}

// ---------------- degree + D^-1/2 ----------------
__global__ __launch_bounds__(256)
void k_rowsum(const float* __restrict__ A, float* __restrict__ dinv, int M3)
{
    __shared__ float red[4];
    int r = blockIdx.x, tid = threadIdx.x;
    float s = 0.f;
    for (int c = tid; c < LDAB; c += 256) s += A[(size_t)r*LDAB + c];
    #pragma unroll
    for (int off = 32; off > 0; off >>= 1) s += __shfl_down(s, off, 64);
    if ((tid & 63) == 0) red[tid >> 6] = s;
    __syncthreads();
    if (tid == 0){
        float tot = red[0] + red[1] + red[2] + red[3];
        dinv[r] = (tot > 0.f) ? 1.f / sqrtf(tot) : 0.f;
    }
}

// ---------------- scale + bf16 copy ----------------
__global__ void k_scale(float* __restrict__ A, us* __restrict__ Abf,
                        const float* __restrict__ dinv, int M3)
{
    int c = blockIdx.x*16 + threadIdx.x;
    int r = blockIdx.y*16 + threadIdx.y;
    if (r < M3 && c < M3){
        float v = A[(size_t)r*LDAB + c] * dinv[r]*dinv[c];
        A[(size_t)r*LDAB + c] = v;
        Abf[(size_t)r*LDAB + c] = f2b(v);
    }
}

// ---------------- h0 = relu(x @ W_in + b_in) (permuted rows) ----------------
__global__ __launch_bounds__(256)
void k_gemm_h0(const float* __restrict__ x, const float* __restrict__ Win,
               const float* __restrict__ bin, float* __restrict__ h0,
               us* __restrict__ h0b, us* __restrict__ h0bT, int M3)
{
    __shared__ float As[16][68];
    __shared__ float Bs[16][64];
    int i0 = blockIdx.y*64, j0 = blockIdx.x*64;
    int tid = threadIdx.x;
    int ty = tid >> 4, tx = tid & 15;
    int lr = tid >> 2, lk = (tid & 3) << 2;
    int br = tid >> 4, bc = (tid & 15) << 2;
    float acc[4][4] = {};
    for (int k0 = 0; k0 < 320; k0 += 16){
        float4 av = *(const float4*)&x[(size_t)(i0+lr)*LDX + k0 + lk];
        float4 bwv;
        {
            int kr = k0 + br;
            int c0 = j0 + bc;
            if (kr < 300 && c0 + 3 < 500){
                bwv = *(const float4*)&Win[(size_t)kr*500 + c0];
            } else {
                bwv.x = (kr < 300 && c0+0 < 500) ? Win[(size_t)kr*500 + c0+0] : 0.f;
                bwv.y = (kr < 300 && c0+1 < 500) ? Win[(size_t)kr*500 + c0+1] : 0.f;
                bwv.z = (kr < 300 && c0+2 < 500) ? Win[(size_t)kr*500 + c0+2] : 0.f;
                bwv.w = (kr < 300 && c0+3 < 500) ? Win[(size_t)kr*500 + c0+3] : 0.f;
            }
        }
        __syncthreads();
        As[lk+0][lr] = av.x; As[lk+1][lr] = av.y; As[lk+2][lr] = av.z; As[lk+3][lr] = av.w;
        *(float4*)&Bs[br][bc] = bwv;
        __syncthreads();
        #pragma unroll
        for (int kk = 0; kk < 16; ++kk){
            float4 a4 = *(const float4*)&As[kk][ty*4];
            float4 b4 = *(const float4*)&Bs[kk][tx*4];
            float a_[4] = {a4.x, a4.y, a4.z, a4.w};
            float b_[4] = {b4.x, b4.y, b4.z, b4.w};
            #pragma unroll
            for (int u = 0; u < 4; ++u)
                #pragma unroll
                for (int v = 0; v < 4; ++v) acc[u][v] += a_[u]*b_[v];
        }
    }
    #pragma unroll
    for (int u = 0; u < 4; ++u){
        int i = i0 + ty*4 + u;
        #pragma unroll
        for (int v = 0; v < 4; ++v){
            int j = j0 + tx*4 + v;
            float val = 0.f;
            if (i < M3 && j < 500) val = fmaxf(acc[u][v] + bin[j], 0.f);
            h0[(size_t)i*LDH + j] = val;
            us bv = f2b(val);
            h0b[(size_t)i*LDH + j] = bv;
            h0bT[(size_t)j*LDR + i] = bv;
        }
    }
}

// ---------------- convert ALL 64 layers of W to bf16 transposed ----------------
__global__ __launch_bounds__(256)
void k_wtr(const float* __restrict__ Wc, us* __restrict__ Wt)
{
    __shared__ us sT[64][72];
    int l = blockIdx.z;
    int k0 = blockIdx.x*64, j0 = blockIdx.y*64;
    const float* W = Wc + (size_t)l*500000;
    int ksrc0 = (k0 < 512) ? k0 : k0 - 12;
    int klim  = (k0 < 512) ? 500 : 1000;
    int t = threadIdx.x;
    #pragma unroll
    for (int rr = 0; rr < 4; ++rr){
        int kl = (t >> 4) + rr*16;
        int k  = ksrc0 + kl;
        int jl = (t & 15) * 4;
        int j  = j0 + jl;
        bool vk = (k < klim);
        float4 v;
        if (vk && j + 3 < 500){
            v = *(const float4*)&W[(size_t)k*500 + j];
        } else {
            v.x = (vk && j+0 < 500) ? W[(size_t)k*500 + j+0] : 0.f;
            v.y = (vk && j+1 < 500) ? W[(size_t)k*500 + j+1] : 0.f;
            v.z = (vk && j+2 < 500) ? W[(size_t)k*500 + j+2] : 0.f;
            v.w = (vk && j+3 < 500) ? W[(size_t)k*500 + j+3] : 0.f;
        }
        sT[jl+0][kl] = f2b(v.x);
        sT[jl+1][kl] = f2b(v.y);
        sT[jl+2][kl] = f2b(v.z);
        sT[jl+3][kl] = f2b(v.w);
    }
    __syncthreads();
    int jl = t >> 2, kc = (t & 3) * 16;
    us* dst = Wt + (size_t)l*LDH*1024 + (size_t)(j0+jl)*1024 + k0 + kc;
    *(uint4*)&dst[0] = *(const uint4*)&sT[jl][kc];
    *(uint4*)&dst[8] = *(const uint4*)&sT[jl][kc+8];
}

// ---------------- fused per-layer kernel: LDS-staged GEMM1 slab + GEMM2 + epilogue ----------
// grid 160 = (it 20) x (jt 8); block 512 = 8 waves
// LDS map: [0,64K) sH (GEMM1 B-stage) -> slab (GEMM2 A);  [64K,81K) sepF;
//          [81K,+8K) sA/sW;  [+8K] sH0.   total 99,328 B
__global__ __launch_bounds__(512)
void k_layer5(const us* __restrict__ Abf, const us* __restrict__ src,
              const float* __restrict__ h0, const us* __restrict__ h0b,
              const us* __restrict__ Wl, const int* __restrict__ tileK,
              float th, us* __restrict__ dst)
{
    __shared__ __align__(16) char smem[99328];
    us*    sH   = (us*)smem;                 // [512][64] swizzled
    us*    slab = (us*)smem;                 // [64][512] swizzled (after GEMM1)
    float* sepF = (float*)(smem + 65536);    // [64][68]
    us*    sA   = (us*)(smem + 82944);       // [64][64] swizzled
    us*    sW   = (us*)(smem + 82944);       // [64][64] swizzled (GEMM2)
    us*    sH0  = (us*)(smem + 91136);       // [64][64] swizzled (GEMM2)

    const int tid = threadIdx.x, lane = tid & 63, w = tid >> 6;
    const int lm = lane & 15, lq = lane >> 4;
    const int it = blockIdx.x >> 3, jt = blockIdx.x & 7;
    const int i0 = it*64, j0 = jt*64;
    const int kminf = tileK[it] & ~63;
    const int kmax  = tileK[20 + it];
    const int T = (kmax - kminf + 63) >> 6;

    const int srow = tid >> 3;           // staging row 0..63
    const int sc   = (tid & 7) * 8;      // staging us-col (16B granule)

    // ===== GEMM1: hi slab 64x512, banded K, staged LDS =====
    uint4 pA = *(const uint4*)&Abf[(size_t)(i0+srow)*LDAB + kminf + sc];
    uint4 pH[8];
    #pragma unroll
    for (int j = 0; j < 8; ++j){
        int cid = tid + 512*j;
        pH[j] = *(const uint4*)&src[(size_t)(cid>>3)*LDR + kminf + (cid&7)*8];
    }
    f32x4 accS[4][4] = {};
    for (int t = 0; t < T; ++t){
        __syncthreads();
        *(uint4*)&sA[SWZ(srow, sc)] = pA;
        #pragma unroll
        for (int j = 0; j < 8; ++j){
            int cid = tid + 512*j;
            *(uint4*)&sH[SWZ(cid>>3, (cid&7)*8)] = pH[j];
        }
        if (t + 1 < T){
            int kb = kminf + (t+1)*64;
            pA = *(const uint4*)&Abf[(size_t)(i0+srow)*LDAB + kb + sc];
            #pragma unroll
            for (int j = 0; j < 8; ++j){
                int cid = tid + 512*j;
                pH[j] = *(const uint4*)&src[(size_t)(cid>>3)*LDR + kb + (cid&7)*8];
            }
        }
        __syncthreads();
        #pragma unroll
        for (int ks = 0; ks < 2; ++ks){
            int kk = ks*32 + lq*8;
            short8 af[4], bf[4];
            #pragma unroll
            for (int fr = 0; fr < 4; ++fr)
                af[fr] = *(const short8*)&sA[SWZ(fr*16 + lm, kk)];
            #pragma unroll
            for (int fc = 0; fc < 4; ++fc)
                bf[fc] = *(const short8*)&sH[SWZ(w*64 + fc*16 + lm, kk)];
            #pragma unroll
            for (int fr = 0; fr < 4; ++fr)
                #pragma unroll
                for (int fc = 0; fc < 4; ++fc)
                    accS[fr][fc] = __builtin_amdgcn_mfma_f32_16x16x32_bf16(af[fr], bf[fc], accS[fr][fc], 0, 0, 0);
        }
    }
    __syncthreads();   // sH dead; region becomes slab

    // write slab (bf16, swizzled stride-512) + fp32 window for this block's jt column
    #pragma unroll
    for (int fr = 0; fr < 4; ++fr)
        #pragma unroll
        for (int fc = 0; fc < 4; ++fc)
            #pragma unroll
            for (int rg = 0; rg < 4; ++rg){
                int row = fr*16 + lq*4 + rg;
                int col = w*64 + fc*16 + lm;
                float v = accS[fr][fc][rg];
                slab[row*512 + (col ^ ((row&7)<<3))] = f2b(v);
                if (w == jt) sepF[row*68 + fc*16 + lm] = v;
            }
    __syncthreads();

    // ===== GEMM2: out 64x64, K=1024 (slab | h0b), staged W =====
    const int r16 = (w & 3) * 16, cb = (w >> 2) * 32;
    uint4 pW = *(const uint4*)&Wl[(size_t)(j0+srow)*1024 + sc];
    uint4 pH0 = {};
    f32x4 accG[2] = {};
    for (int s = 0; s < 16; ++s){
        __syncthreads();
        *(uint4*)&sW[SWZ(srow, sc)] = pW;
        if (s >= 8) *(uint4*)&sH0[SWZ(srow, sc)] = pH0;
        if (s + 1 < 16){
            pW = *(const uint4*)&Wl[(size_t)(j0+srow)*1024 + (s+1)*64 + sc];
            if (s + 1 >= 8)
                pH0 = *(const uint4*)&h0b[(size_t)(i0+srow)*LDH + (s+1)*64 - 512 + sc];
        }
        __syncthreads();
        #pragma unroll
        for (int ks = 0; ks < 2; ++ks){
            int kk = ks*32 + lq*8;
            short8 a;
            if (s < 8){
                int node = r16 + lm, kp = s*64 + kk;
                a = *(const short8*)&slab[node*512 + (kp ^ ((node&7)<<3))];
            } else {
                a = *(const short8*)&sH0[SWZ(r16 + lm, kk)];
            }
            #pragma unroll
            for (int fc = 0; fc < 2; ++fc){
                short8 b = *(const short8*)&sW[SWZ(cb + fc*16 + lm, kk)];
                accG[fc] = __builtin_amdgcn_mfma_f32_16x16x32_bf16(a, b, accG[fc], 0, 0, 0);
            }
        }
    }

    // ===== epilogue =====
    float cth = 1.f - th;
    #pragma unroll
    for (int fc = 0; fc < 2; ++fc){
        unsigned int pk[2];
        unsigned int tmp0 = 0, tmp1 = 0;
        #pragma unroll
        for (int rg = 0; rg < 4; ++rg){
            int il = r16 + lq*4 + rg;
            int jl = cb + fc*16 + lm;
            float hiv = sepF[il*68 + jl];
            float h0v = h0[(size_t)(i0 + il)*LDH + j0 + jl];
            float o = fmaxf(th*accG[fc][rg] + cth*(0.9f*hiv + 0.1f*h0v), 0.f);
            unsigned int ob = (unsigned int)f2b(o);
            if (rg < 2) tmp0 |= ob << (16*rg);
            else        tmp1 |= ob << (16*(rg-2));
        }
        pk[0] = tmp0; pk[1] = tmp1;
        int jg = j0 + cb + fc*16 + lm;
        int ig = i0 + r16 + lq*4;
        *(uint2*)&dst[(size_t)jg*LDR + ig] = *(uint2*)pk;
    }
}

// ---------------- final classify + log_softmax ----------------
__global__ void k_final(const us* __restrict__ hT, const float* __restrict__ Wfc,
                        const float* __restrict__ bfc, const int* __restrict__ rmap3,
                        float* __restrict__ out, int N)
{
    int i = blockIdx.x, lane = threadIdx.x;
    int p0 = rmap3[i], p1 = rmap3[448 + i], p2 = rmap3[896 + i];
    float acc[7] = {};
    for (int k = lane; k < 1500; k += 64){
        int m = (k >= 1000) ? 2 : ((k >= 500) ? 1 : 0);
        int kk = k - m*500;
        int prow = (m == 0) ? p0 : (m == 1) ? p1 : p2;
        float f = fmaxf(b2f(hT[(size_t)kk*LDR + prow]), 0.f);
        #pragma unroll
        for (int c = 0; c < 7; ++c) acc[c] += f * Wfc[(size_t)k*7 + c];
    }
    #pragma unroll
    for (int off = 32; off > 0; off >>= 1){
        #pragma unroll
        for (int c = 0; c < 7; ++c) acc[c] += __shfl_down(acc[c], off, 64);
    }
    if (lane == 0){
        float lg[7], mx = -1e30f;
        #pragma unroll
        for (int c = 0; c < 7; ++c){ lg[c] = acc[c] + bfc[c]; mx = fmaxf(mx, lg[c]); }
        float s = 0.f;
        #pragma unroll
        for (int c = 0; c < 7; ++c) s += expf(lg[c] - mx);
        float lse = mx + logf(s);
        #pragma unroll
        for (int c = 0; c < 7; ++c) out[(size_t)i*7 + c] = lg[c] - lse;
    }
}

extern "C" void kernel_launch(void* const* d_in, const int* in_sizes, int n_in,
                              void* d_out, int out_size, void* d_ws, size_t ws_size,
                              hipStream_t stream)
{
    const float* speaker = (const float*)d_in[1];
    const float* fea_a   = (const float*)d_in[2];
    const float* fea_v   = (const float*)d_in[3];
    const float* fea_t   = (const float*)d_in[4];
    const float* Wa      = (const float*)d_in[5];
    const float* ba      = (const float*)d_in[6];
    const float* Wv      = (const float*)d_in[7];
    const float* bv      = (const float*)d_in[8];
    const float* Wt_in   = (const float*)d_in[9];
    const float* bt      = (const float*)d_in[10];
    const float* spk_emb = (const float*)d_in[11];
    const float* W_in    = (const float*)d_in[12];
    const float* b_in    = (const float*)d_in[13];
    const float* W_convs = (const float*)d_in[14];
    const float* W_fc1   = (const float*)d_in[15];
    const float* b_fc1   = (const float*)d_in[16];
    const int* seq = (const int*)d_in[18];
    const int* bat = (const int*)d_in[19];
    const int* dia = (const int*)d_in[20];

    const int N  = in_sizes[18];   // 411
    const int M3 = 3*N;            // 1233

    char* wsb = (char*)d_ws;
    float* A     = (float*)(wsb + 0);             // 1344*1344*4 = 7,225,344
    us*    Abf   = (us*)   (wsb + 8388608);       // 3,612,672
    float* x     = (float*)(wsb + 12582912);
    float* fn    = (float*)(wsb + 14680064);
    float* h0    = (float*)(wsb + 16777216);
    us*    h0b   = (us*)   (wsb + 19922944);
    us*    h0bT  = (us*)   (wsb + 21495808);      // 512*1344*2
    us*    hTa   = (us*)   (wsb + 23068672);
    us*    hTb   = (us*)   (wsb + 24641536);
    us*    Wt    = (us*)   (wsb + 33554432);      // 64*512*1024*2 = 67,108,864
    float* dinv  = (float*)(wsb + 100663296);
    int*   off13 = (int*)  (wsb + 100669440);
    int*   rmap3 = (int*)  (wsb + 100670464);
    int*   tileK = (int*)  (wsb + 100676608);
    int*   spki  = (int*)  (wsb + 100853760);
    float* xga   = (float*)(wsb + 100859904);
    float* xgv   = (float*)(wsb + 103727104);
    float* xgt   = (float*)(wsb + 104415232);
    float* WaT   = (float*)(wsb + 106250240);
    float* WvT   = (float*)(wsb + 108170240);
    float* WtT   = (float*)(wsb + 108631040);
    float* xpa   = (float*)(wsb + 109859840);
    float* xpv   = (float*)(wsb + 112153600);
    float* xpt   = (float*)(wsb + 113300480);

    hipMemsetAsync(A,    0, 7225344, stream);
    hipMemsetAsync(Abf,  0, 3612672, stream);
    hipMemsetAsync(x,    0, 1638400, stream);
    hipMemsetAsync(fn,   0, 1638400, stream);
    hipMemsetAsync(h0bT, 0, 1376256, stream);
    hipMemsetAsync(hTa,  0, 1376256, stream);
    hipMemsetAsync(hTb,  0, 1376256, stream);

    k_offsets<<<1, 64, 0, stream>>>(dia, N, off13, rmap3, tileK);
    k_gather<<<448, 256, 0, stream>>>(fea_a, fea_v, fea_t, speaker, seq, bat, xga, xgv, xgt, spki, N);

    k_trw<<<dim3(25, 5), 256, 0, stream>>>(Wa,    1582, 1600, WaT);
    k_trw<<<dim3( 6, 5), 256, 0, stream>>>(Wv,     342,  384, WvT);
    k_trw<<<dim3(16, 5), 256, 0, stream>>>(Wt_in, 1024, 1024, WtT);

    k_projg2<<<dim3(5, 7, 4), 256, 0, stream>>>(xga, 1600, 400, WaT, xpa);
    k_projg2<<<dim3(5, 7, 2), 256, 0, stream>>>(xgv,  384, 192, WvT, xpv);
    k_projg2<<<dim3(5, 7, 4), 256, 0, stream>>>(xgt, 1024, 256, WtT, xpt);

    k_norm2<<<M3, 256, 0, stream>>>(xpa, xpv, xpt, ba, bv, bt, spk_emb, spki, rmap3, x, fn, N);

    int nt = (N + 31)/32;
    k_intra<<<dim3(nt, nt, 3), dim3(16,16), 0, stream>>>(fn, dia, rmap3, A, N);
    k_cross<<<N, 64, 0, stream>>>(fn, rmap3, A, N);
    k_rowsum<<<M3, 256, 0, stream>>>(A, dinv, M3);
    k_scale<<<dim3(78, 78), dim3(16,16), 0, stream>>>(A, Abf, dinv, M3);

    k_gemm_h0<<<dim3(8, 20), 256, 0, stream>>>(x, W_in, b_in, h0, h0b, h0bT, M3);
    k_wtr<<<dim3(16, 8, 64), 256, 0, stream>>>(W_convs, Wt);

    const us* srcp = h0bT;
    for (int l = 1; l <= 64; ++l){
        us* dstp = ((l-1) & 1) ? hTb : hTa;
        float thv = logf(0.5f/(float)l + 1.0f);
        k_layer5<<<160, 512, 0, stream>>>(Abf, srcp, h0, h0b,
                                          Wt + (size_t)(l-1)*LDH*1024, tileK, thv, dstp);
        srcp = dstp;
    }

    k_final<<<N, 64, 0, stream>>>(hTb, W_fc1, b_fc1, rmap3, (float*)d_out, N);
}

// Round 9
// 2607.173 us; speedup vs baseline: 1.0979x; 1.0023x over previous
//
#include <hip/hip_runtime.h>
#include <hip/hip_bf16.h>
#include <math.h>

#define LDAB 1344  // A_perm col stride (1233 -> 1344)
#define LDR  1344  // hT row capacity
#define LDH  512   // padded G (500 -> 512)
#define LDX  320   // padded H (300 -> 320)

typedef __attribute__((ext_vector_type(8))) short short8;
typedef __attribute__((ext_vector_type(4))) float f32x4;
typedef unsigned short us;

__device__ __forceinline__ us f2b(float x){
    unsigned int u = __float_as_uint(x);
    return (us)((u + 0x7fffu + ((u >> 16) & 1u)) >> 16);
}
__device__ __forceinline__ float b2f(us u){ return __uint_as_float(((unsigned int)u) << 16); }

__device__ __forceinline__ float arc_sim(float c){
    float cc = fminf(1.f, fmaxf(-1.f, c * 0.99999f));
    return 1.f - acosf(cc) * 0.31830988618379067f;
}

#define SWZ(r, k) (((r)*64 + (k)) ^ (((r)&7)<<3))

// ---------------- offsets / permutation map / tile bands ----------------
__global__ void k_offsets(const int* __restrict__ dia, int N,
                          int* __restrict__ off13, int* __restrict__ rmap3, int* __restrict__ tileK)
{
    __shared__ int soff[13], slen[12];
    if (threadIdx.x == 0){
        int d = 0; soff[0] = 0;
        for (int i = 0; i < N; ++i){
            while (dia[i] > d){ ++d; soff[d] = i; }
        }
        for (int dd = d+1; dd <= 12; ++dd) soff[dd] = N;
        for (int dd = 0; dd < 12; ++dd) slen[dd] = soff[dd+1] - soff[dd];
        for (int dd = 0; dd < 13; ++dd) off13[dd] = soff[dd];
    }
    __syncthreads();
    for (int i = threadIdx.x; i < N; i += 64){
        int d = dia[i];
        int base = 3*soff[d], u = i - soff[d], l = slen[d];
        rmap3[0*448 + i] = base + u;
        rmap3[1*448 + i] = base + l + u;
        rmap3[2*448 + i] = base + 2*l + u;
    }
    if (threadIdx.x < 20){
        int it = threadIdx.x;
        int r0 = it*64, r1 = min(it*64 + 63, 3*N - 1);
        int dfirst = 11, dlast = 11;
        for (int dd = 0; dd < 12; ++dd){ if (r0 < 3*soff[dd+1]){ dfirst = dd; break; } }
        for (int dd = 0; dd < 12; ++dd){ if (r1 < 3*soff[dd+1]){ dlast = dd; break; } }
        tileK[it]      = (3*soff[dfirst]) & ~63;       // floored to 64 for aligned K-steps
        tileK[20 + it] = 3*soff[dlast] + 3*slen[dlast];
    }
}

// ---------------- gather ragged utterances into padded buffers + speaker idx ----------------
__global__ __launch_bounds__(256)
void k_gather(const float* __restrict__ fa, const float* __restrict__ fv, const float* __restrict__ ft,
              const float* __restrict__ speaker, const int* __restrict__ seq, const int* __restrict__ bat,
              float* __restrict__ xga, float* __restrict__ xgv, float* __restrict__ xgt,
              int* __restrict__ spki, int N)
{
    int i = blockIdx.x;
    int tid = threadIdx.x;
    bool real = i < N;
    int s = real ? seq[i] : 0, b = real ? bat[i] : 0;
    size_t base = (size_t)(s*12 + b);
    for (int k = tid; k < 1600; k += 256) xga[(size_t)i*1600 + k] = (real && k < 1582) ? fa[base*1582 + k] : 0.f;
    for (int k = tid; k < 384;  k += 256) xgv[(size_t)i*384  + k] = (real && k < 342)  ? fv[base*342  + k] : 0.f;
    for (int k = tid; k < 1024; k += 256) xgt[(size_t)i*1024 + k] = real ? ft[base*1024 + k] : 0.f;
    if (tid == 0){
        int bi = 0;
        if (real){
            const float* sp = speaker + base*9;
            float best = sp[0];
            for (int c = 1; c < 9; ++c) if (sp[c] > best){ best = sp[c]; bi = c; }
        }
        spki[i] = bi;
    }
}

// ---------------- transpose projection weight W[D][300] -> WT[300][Kp] fp32 ----------------
__global__ __launch_bounds__(256)
void k_trw(const float* __restrict__ W, int D, int Kp, float* __restrict__ WTr)
{
    __shared__ float tt[64][65];
    int k0 = blockIdx.x*64, j0 = blockIdx.y*64;
    int t = threadIdx.x;
    #pragma unroll
    for (int rr = 0; rr < 4; ++rr){
        int kl = (t >> 4) + rr*16;
        int k  = k0 + kl;
        int jl = (t & 15) * 4;
        int j  = j0 + jl;
        float4 v;
        if (k < D && j + 3 < 300){
            v = *(const float4*)&W[(size_t)k*300 + j];
        } else {
            v.x = (k < D && j+0 < 300) ? W[(size_t)k*300 + j+0] : 0.f;
            v.y = (k < D && j+1 < 300) ? W[(size_t)k*300 + j+1] : 0.f;
            v.z = (k < D && j+2 < 300) ? W[(size_t)k*300 + j+2] : 0.f;
            v.w = (k < D && j+3 < 300) ? W[(size_t)k*300 + j+3] : 0.f;
        }
        tt[jl+0][kl] = v.x; tt[jl+1][kl] = v.y; tt[jl+2][kl] = v.z; tt[jl+3][kl] = v.w;
    }
    __syncthreads();
    #pragma unroll
    for (int rr = 0; rr < 4; ++rr){
        int jl = (t >> 4) + rr*16;
        int j  = j0 + jl;
        int kq = (t & 15) * 4;
        if (j < 300){
            float4 o; o.x = tt[jl][kq]; o.y = tt[jl][kq+1]; o.z = tt[jl][kq+2]; o.w = tt[jl][kq+3];
            *(float4*)&WTr[(size_t)j*Kp + k0 + kq] = o;
        }
    }
}

// ---------------- projection GEMM partials (split-K) ----------------
__global__ __launch_bounds__(256)
void k_projg2(const float* __restrict__ xg, int Kp, int kslice,
              const float* __restrict__ WTr, float* __restrict__ xp)
{
    __shared__ float As[16][68];
    __shared__ float Bs[16][64];
    int i0 = blockIdx.y*64, j0 = blockIdx.x*64;
    int ks0 = blockIdx.z * kslice;
    int tid = threadIdx.x;
    int ty = tid >> 4, tx = tid & 15;
    int lr = tid >> 2, lk = (tid & 3) << 2;
    int bj = tid & 63, bk4 = (tid >> 6) << 2;
    float acc[4][4] = {};
    for (int k0 = 0; k0 < kslice; k0 += 16){
        float4 av = *(const float4*)&xg[(size_t)(i0+lr)*Kp + ks0 + k0 + lk];
        float4 wv = {0.f, 0.f, 0.f, 0.f};
        int j = j0 + bj;
        if (j < 300) wv = *(const float4*)&WTr[(size_t)j*Kp + ks0 + k0 + bk4];
        __syncthreads();
        As[lk+0][lr] = av.x; As[lk+1][lr] = av.y; As[lk+2][lr] = av.z; As[lk+3][lr] = av.w;
        Bs[bk4+0][bj] = wv.x; Bs[bk4+1][bj] = wv.y; Bs[bk4+2][bj] = wv.z; Bs[bk4+3][bj] = wv.w;
        __syncthreads();
        #pragma unroll
        for (int kk = 0; kk < 16; ++kk){
            float4 a4 = *(const float4*)&As[kk][ty*4];
            float4 b4 = *(const float4*)&Bs[kk][tx*4];
            float a_[4] = {a4.x, a4.y, a4.z, a4.w};
            float b_[4] = {b4.x, b4.y, b4.z, b4.w};
            #pragma unroll
            for (int u = 0; u < 4; ++u)
                #pragma unroll
                for (int v = 0; v < 4; ++v) acc[u][v] += a_[u]*b_[v];
        }
    }
    #pragma unroll
    for (int u = 0; u < 4; ++u){
        int i = i0 + ty*4 + u;
        #pragma unroll
        for (int v = 0; v < 4; ++v)
            xp[((size_t)blockIdx.z*448 + i)*320 + j0 + tx*4 + v] = acc[u][v];
    }
}

// ---------------- reduce split-K + bias + spk -> x (PERMUTED rows) and fn ----------------
__global__ __launch_bounds__(256)
void k_norm2(const float* __restrict__ xpa, const float* __restrict__ xpv, const float* __restrict__ xpt,
             const float* __restrict__ ba, const float* __restrict__ bv, const float* __restrict__ bt,
             const float* __restrict__ spk_emb, const int* __restrict__ spki,
             const int* __restrict__ rmap3,
             float* __restrict__ x, float* __restrict__ fn, int N)
{
    __shared__ float red[4];
    int r = blockIdx.x, tid = threadIdx.x;
    int m = (r >= 2*N) ? 2 : (r >= N ? 1 : 0);
    int n = r - m*N;
    const float* xp   = (m==0) ? xpa : (m==1) ? xpv : xpt;
    const float* bias = (m==0) ? ba  : (m==1) ? bv  : bt;
    int KS = (m==1) ? 2 : 4;
    float v0 = 0.f, v1 = 0.f;
    int j0 = tid, j1 = tid + 256;
    if (j0 < 300){
        float s = bias[j0];
        for (int si = 0; si < KS; ++si) s += xp[((size_t)si*448 + n)*320 + j0];
        if (m == 2) s += spk_emb[spki[n]*300 + j0];
        v0 = s;
    }
    if (j1 < 300){
        float s = bias[j1];
        for (int si = 0; si < KS; ++si) s += xp[((size_t)si*448 + n)*320 + j1];
        if (m == 2) s += spk_emb[spki[n]*300 + j1];
        v1 = s;
    }
    float ss = v0*v0 + v1*v1;
    #pragma unroll
    for (int off = 32; off > 0; off >>= 1) ss += __shfl_down(ss, off, 64);
    if ((tid & 63) == 0) red[tid >> 6] = ss;
    __syncthreads();
    float tot = red[0] + red[1] + red[2] + red[3];
    float inv = 1.f / (sqrtf(tot) + 1e-8f);
    int prow = rmap3[m*448 + n];
    x [(size_t)prow*LDX + j0] = v0;
    fn[(size_t)r*LDX + j0] = v0 * inv;
    if (j1 < 320){
        x [(size_t)prow*LDX + j1] = v1;
        fn[(size_t)r*LDX + j1] = v1 * inv;
    }
}

// ---------------- intra-modal adjacency -> PERMUTED block-diagonal A ----------------
__global__ __launch_bounds__(256)
void k_intra(const float* __restrict__ fn, const int* __restrict__ dia,
             const int* __restrict__ rmap3, float* __restrict__ A, int N)
{
    int m  = blockIdx.z;
    int i0 = blockIdx.y * 32, j0 = blockIdx.x * 32;
    int iend = min(i0 + 31, N - 1), jend = min(j0 + 31, N - 1);
    if (dia[iend] < dia[j0] || dia[jend] < dia[i0]) return;

    __shared__ float As[32][17], Bs[32][17];
    int tx = threadIdx.x, ty = threadIdx.y;
    int tid = ty*16 + tx;
    float acc[2][2] = {};
    for (int k0 = 0; k0 < 320; k0 += 16){
        __syncthreads();
        for (int l = tid; l < 512; l += 256){
            int r = l >> 4, kk = l & 15;
            int gi = i0 + r, gj = j0 + r;
            As[r][kk] = (gi < N) ? fn[((size_t)m*N + gi)*LDX + k0 + kk] : 0.f;
            Bs[r][kk] = (gj < N) ? fn[((size_t)m*N + gj)*LDX + k0 + kk] : 0.f;
        }
        __syncthreads();
        #pragma unroll
        for (int kk = 0; kk < 16; ++kk){
            float a0 = As[ty*2+0][kk], a1 = As[ty*2+1][kk];
            float b0 = Bs[tx*2+0][kk], b1 = Bs[tx*2+1][kk];
            acc[0][0] += a0*b0; acc[0][1] += a0*b1;
            acc[1][0] += a1*b0; acc[1][1] += a1*b1;
        }
    }
    #pragma unroll
    for (int u = 0; u < 2; ++u)
        #pragma unroll
        for (int v = 0; v < 2; ++v){
            int i = i0 + ty*2 + u, j = j0 + tx*2 + v;
            if (i < N && j < N && dia[i] == dia[j]){
                int pi = rmap3[m*448 + i], pj = rmap3[m*448 + j];
                A[(size_t)pi*LDAB + pj] = arc_sim(acc[u][v]);
            }
        }
}

// ---------------- cross-modal diagonal links (permuted) ----------------
__global__ void k_cross(const float* __restrict__ fn, const int* __restrict__ rmap3,
                        float* __restrict__ A, int N)
{
    int i = blockIdx.x, lane = threadIdx.x;
    float d01 = 0.f, d02 = 0.f, d12 = 0.f;
    for (int k = lane; k < 300; k += 64){
        float a = fn[((size_t)0*N + i)*LDX + k];
        float b = fn[((size_t)1*N + i)*LDX + k];
        float c = fn[((size_t)2*N + i)*LDX + k];
        d01 += a*b; d02 += a*c; d12 += b*c;
    }
    #pragma unroll
    for (int off = 32; off > 0; off >>= 1){
        d01 += __shfl_down(d01, off, 64);
        d02 += __shfl_down(d02, off, 64);
        d12 += __shfl_down(d12, off, 64);
    }
    if (lane == 0){
        float s01 = arc_sim(d01), s02 = arc_sim(d02), s12 = arc_sim(d12);
        size_t p0 = rmap3[i], p1 = rmap3[448 + i], p2 = rmap3[896 + i];
        A[p0*LDAB + p1] = s01; A[p1*LDAB + p0] = s01;
        A[p0*LDAB + p2] = s02; A[p2*LDAB + p0] = s02;
        A[p1*LDAB + p2] = s12; A[p2*LDAB + p1] = s12;
    }
}

// ---------------- degree + D^-1/2 ----------------
__global__ __launch_bounds__(256)
void k_rowsum(const float* __restrict__ A, float* __restrict__ dinv, int M3)
{
    __shared__ float red[4];
    int r = blockIdx.x, tid = threadIdx.x;
    float s = 0.f;
    for (int c = tid; c < LDAB; c += 256) s += A[(size_t)r*LDAB + c];
    #pragma unroll
    for (int off = 32; off > 0; off >>= 1) s += __shfl_down(s, off, 64);
    if ((tid & 63) == 0) red[tid >> 6] = s;
    __syncthreads();
    if (tid == 0){
        float tot = red[0] + red[1] + red[2] + red[3];
        dinv[r] = (tot > 0.f) ? 1.f / sqrtf(tot) : 0.f;
    }
}

// ---------------- scale + bf16 copy ----------------
__global__ void k_scale(float* __restrict__ A, us* __restrict__ Abf,
                        const float* __restrict__ dinv, int M3)
{
    int c = blockIdx.x*16 + threadIdx.x;
    int r = blockIdx.y*16 + threadIdx.y;
    if (r < M3 && c < M3){
        float v = A[(size_t)r*LDAB + c] * dinv[r]*dinv[c];
        A[(size_t)r*LDAB + c] = v;
        Abf[(size_t)r*LDAB + c] = f2b(v);
    }
}

// ---------------- h0 = relu(x @ W_in + b_in) (permuted rows) ----------------
__global__ __launch_bounds__(256)
void k_gemm_h0(const float* __restrict__ x, const float* __restrict__ Win,
               const float* __restrict__ bin, float* __restrict__ h0,
               us* __restrict__ h0b, us* __restrict__ h0bT, int M3)
{
    __shared__ float As[16][68];
    __shared__ float Bs[16][64];
    int i0 = blockIdx.y*64, j0 = blockIdx.x*64;
    int tid = threadIdx.x;
    int ty = tid >> 4, tx = tid & 15;
    int lr = tid >> 2, lk = (tid & 3) << 2;
    int br = tid >> 4, bc = (tid & 15) << 2;
    float acc[4][4] = {};
    for (int k0 = 0; k0 < 320; k0 += 16){
        float4 av = *(const float4*)&x[(size_t)(i0+lr)*LDX + k0 + lk];
        float4 bwv;
        {
            int kr = k0 + br;
            int c0 = j0 + bc;
            if (kr < 300 && c0 + 3 < 500){
                bwv = *(const float4*)&Win[(size_t)kr*500 + c0];
            } else {
                bwv.x = (kr < 300 && c0+0 < 500) ? Win[(size_t)kr*500 + c0+0] : 0.f;
                bwv.y = (kr < 300 && c0+1 < 500) ? Win[(size_t)kr*500 + c0+1] : 0.f;
                bwv.z = (kr < 300 && c0+2 < 500) ? Win[(size_t)kr*500 + c0+2] : 0.f;
                bwv.w = (kr < 300 && c0+3 < 500) ? Win[(size_t)kr*500 + c0+3] : 0.f;
            }
        }
        __syncthreads();
        As[lk+0][lr] = av.x; As[lk+1][lr] = av.y; As[lk+2][lr] = av.z; As[lk+3][lr] = av.w;
        *(float4*)&Bs[br][bc] = bwv;
        __syncthreads();
        #pragma unroll
        for (int kk = 0; kk < 16; ++kk){
            float4 a4 = *(const float4*)&As[kk][ty*4];
            float4 b4 = *(const float4*)&Bs[kk][tx*4];
            float a_[4] = {a4.x, a4.y, a4.z, a4.w};
            float b_[4] = {b4.x, b4.y, b4.z, b4.w};
            #pragma unroll
            for (int u = 0; u < 4; ++u)
                #pragma unroll
                for (int v = 0; v < 4; ++v) acc[u][v] += a_[u]*b_[v];
        }
    }
    #pragma unroll
    for (int u = 0; u < 4; ++u){
        int i = i0 + ty*4 + u;
        #pragma unroll
        for (int v = 0; v < 4; ++v){
            int j = j0 + tx*4 + v;
            float val = 0.f;
            if (i < M3 && j < 500) val = fmaxf(acc[u][v] + bin[j], 0.f);
            h0[(size_t)i*LDH + j] = val;
            us bv = f2b(val);
            h0b[(size_t)i*LDH + j] = bv;
            h0bT[(size_t)j*LDR + i] = bv;
        }
    }
}

// ---------------- convert ALL 64 layers of W to bf16 transposed ----------------
__global__ __launch_bounds__(256)
void k_wtr(const float* __restrict__ Wc, us* __restrict__ Wt)
{
    __shared__ us sT[64][72];
    int l = blockIdx.z;
    int k0 = blockIdx.x*64, j0 = blockIdx.y*64;
    const float* W = Wc + (size_t)l*500000;
    int ksrc0 = (k0 < 512) ? k0 : k0 - 12;
    int klim  = (k0 < 512) ? 500 : 1000;
    int t = threadIdx.x;
    #pragma unroll
    for (int rr = 0; rr < 4; ++rr){
        int kl = (t >> 4) + rr*16;
        int k  = ksrc0 + kl;
        int jl = (t & 15) * 4;
        int j  = j0 + jl;
        bool vk = (k < klim);
        float4 v;
        if (vk && j + 3 < 500){
            v = *(const float4*)&W[(size_t)k*500 + j];
        } else {
            v.x = (vk && j+0 < 500) ? W[(size_t)k*500 + j+0] : 0.f;
            v.y = (vk && j+1 < 500) ? W[(size_t)k*500 + j+1] : 0.f;
            v.z = (vk && j+2 < 500) ? W[(size_t)k*500 + j+2] : 0.f;
            v.w = (vk && j+3 < 500) ? W[(size_t)k*500 + j+3] : 0.f;
        }
        sT[jl+0][kl] = f2b(v.x);
        sT[jl+1][kl] = f2b(v.y);
        sT[jl+2][kl] = f2b(v.z);
        sT[jl+3][kl] = f2b(v.w);
    }
    __syncthreads();
    int jl = t >> 2, kc = (t & 3) * 16;
    us* dst = Wt + (size_t)l*LDH*1024 + (size_t)(j0+jl)*1024 + k0 + kc;
    *(uint4*)&dst[0] = *(const uint4*)&sT[jl][kc];
    *(uint4*)&dst[8] = *(const uint4*)&sT[jl][kc+8];
}

// ---------------- fused per-layer kernel: LDS-staged GEMM1 slab + GEMM2 + epilogue ----------
// grid 160 = (it 20) x (jt 8); block 512 = 8 waves
// LDS map: [0,64K) sH (GEMM1 B-stage) -> slab (GEMM2 A);  [64K,81K) sepF;
//          [81K,+8K) sA/sW;  [+8K] sH0.   total 99,328 B
__global__ __launch_bounds__(512)
void k_layer5(const us* __restrict__ Abf, const us* __restrict__ src,
              const float* __restrict__ h0, const us* __restrict__ h0b,
              const us* __restrict__ Wl, const int* __restrict__ tileK,
              float th, us* __restrict__ dst)
{
    __shared__ __align__(16) char smem[99328];
    us*    sH   = (us*)smem;                 // [512][64] swizzled
    us*    slab = (us*)smem;                 // [64][512] swizzled (after GEMM1)
    float* sepF = (float*)(smem + 65536);    // [64][68]
    us*    sA   = (us*)(smem + 82944);       // [64][64] swizzled
    us*    sW   = (us*)(smem + 82944);       // [64][64] swizzled (GEMM2)
    us*    sH0  = (us*)(smem + 91136);       // [64][64] swizzled (GEMM2)

    const int tid = threadIdx.x, lane = tid & 63, w = tid >> 6;
    const int lm = lane & 15, lq = lane >> 4;
    const int it = blockIdx.x >> 3, jt = blockIdx.x & 7;
    const int i0 = it*64, j0 = jt*64;
    const int kminf = tileK[it] & ~63;
    const int kmax  = tileK[20 + it];
    const int T = (kmax - kminf + 63) >> 6;

    const int srow = tid >> 3;           // staging row 0..63
    const int sc   = (tid & 7) * 8;      // staging us-col (16B granule)

    // ===== GEMM1: hi slab 64x512, banded K, staged LDS =====
    uint4 pA = *(const uint4*)&Abf[(size_t)(i0+srow)*LDAB + kminf + sc];
    uint4 pH[8];
    #pragma unroll
    for (int j = 0; j < 8; ++j){
        int cid = tid + 512*j;
        pH[j] = *(const uint4*)&src[(size_t)(cid>>3)*LDR + kminf + (cid&7)*8];
    }
    f32x4 accS[4][4] = {};
    for (int t = 0; t < T; ++t){
        __syncthreads();
        *(uint4*)&sA[SWZ(srow, sc)] = pA;
        #pragma unroll
        for (int j = 0; j < 8; ++j){
            int cid = tid + 512*j;
            *(uint4*)&sH[SWZ(cid>>3, (cid&7)*8)] = pH[j];
        }
        if (t + 1 < T){
            int kb = kminf + (t+1)*64;
            pA = *(const uint4*)&Abf[(size_t)(i0+srow)*LDAB + kb + sc];
            #pragma unroll
            for (int j = 0; j < 8; ++j){
                int cid = tid + 512*j;
                pH[j] = *(const uint4*)&src[(size_t)(cid>>3)*LDR + kb + (cid&7)*8];
            }
        }
        __syncthreads();
        #pragma unroll
        for (int ks = 0; ks < 2; ++ks){
            int kk = ks*32 + lq*8;
            short8 af[4], bf[4];
            #pragma unroll
            for (int fr = 0; fr < 4; ++fr)
                af[fr] = *(const short8*)&sA[SWZ(fr*16 + lm, kk)];
            #pragma unroll
            for (int fc = 0; fc < 4; ++fc)
                bf[fc] = *(const short8*)&sH[SWZ(w*64 + fc*16 + lm, kk)];
            #pragma unroll
            for (int fr = 0; fr < 4; ++fr)
                #pragma unroll
                for (int fc = 0; fc < 4; ++fc)
                    accS[fr][fc] = __builtin_amdgcn_mfma_f32_16x16x32_bf16(af[fr], bf[fc], accS[fr][fc], 0, 0, 0);
        }
    }
    __syncthreads();   // sH dead; region becomes slab

    // write slab (bf16, swizzled stride-512) + fp32 window for this block's jt column
    #pragma unroll
    for (int fr = 0; fr < 4; ++fr)
        #pragma unroll
        for (int fc = 0; fc < 4; ++fc)
            #pragma unroll
            for (int rg = 0; rg < 4; ++rg){
                int row = fr*16 + lq*4 + rg;
                int col = w*64 + fc*16 + lm;
                float v = accS[fr][fc][rg];
                slab[row*512 + (col ^ ((row&7)<<3))] = f2b(v);
                if (w == jt) sepF[row*68 + fc*16 + lm] = v;
            }
    __syncthreads();

    // ===== GEMM2: out 64x64, K=1024 (slab | h0b), staged W =====
    const int r16 = (w & 3) * 16, cb = (w >> 2) * 32;
    uint4 pW = *(const uint4*)&Wl[(size_t)(j0+srow)*1024 + sc];
    uint4 pH0 = {};
    f32x4 accG[2] = {};
    for (int s = 0; s < 16; ++s){
        __syncthreads();
        *(uint4*)&sW[SWZ(srow, sc)] = pW;
        if (s >= 8) *(uint4*)&sH0[SWZ(srow, sc)] = pH0;
        if (s + 1 < 16){
            pW = *(const uint4*)&Wl[(size_t)(j0+srow)*1024 + (s+1)*64 + sc];
            if (s + 1 >= 8)
                pH0 = *(const uint4*)&h0b[(size_t)(i0+srow)*LDH + (s+1)*64 - 512 + sc];
        }
        __syncthreads();
        #pragma unroll
        for (int ks = 0; ks < 2; ++ks){
            int kk = ks*32 + lq*8;
            short8 a;
            if (s < 8){
                int node = r16 + lm, kp = s*64 + kk;
                a = *(const short8*)&slab[node*512 + (kp ^ ((node&7)<<3))];
            } else {
                a = *(const short8*)&sH0[SWZ(r16 + lm, kk)];
            }
            #pragma unroll
            for (int fc = 0; fc < 2; ++fc){
                short8 b = *(const short8*)&sW[SWZ(cb + fc*16 + lm, kk)];
                accG[fc] = __builtin_amdgcn_mfma_f32_16x16x32_bf16(a, b, accG[fc], 0, 0, 0);
            }
        }
    }

    // ===== epilogue =====
    float cth = 1.f - th;
    #pragma unroll
    for (int fc = 0; fc < 2; ++fc){
        unsigned int pk[2];
        unsigned int tmp0 = 0, tmp1 = 0;
        #pragma unroll
        for (int rg = 0; rg < 4; ++rg){
            int il = r16 + lq*4 + rg;
            int jl = cb + fc*16 + lm;
            float hiv = sepF[il*68 + jl];
            float h0v = h0[(size_t)(i0 + il)*LDH + j0 + jl];
            float o = fmaxf(th*accG[fc][rg] + cth*(0.9f*hiv + 0.1f*h0v), 0.f);
            unsigned int ob = (unsigned int)f2b(o);
            if (rg < 2) tmp0 |= ob << (16*rg);
            else        tmp1 |= ob << (16*(rg-2));
        }
        pk[0] = tmp0; pk[1] = tmp1;
        int jg = j0 + cb + fc*16 + lm;
        int ig = i0 + r16 + lq*4;
        *(uint2*)&dst[(size_t)jg*LDR + ig] = *(uint2*)pk;
    }
}

// ---------------- final classify + log_softmax ----------------
__global__ void k_final(const us* __restrict__ hT, const float* __restrict__ Wfc,
                        const float* __restrict__ bfc, const int* __restrict__ rmap3,
                        float* __restrict__ out, int N)
{
    int i = blockIdx.x, lane = threadIdx.x;
    int p0 = rmap3[i], p1 = rmap3[448 + i], p2 = rmap3[896 + i];
    float acc[7] = {};
    for (int k = lane; k < 1500; k += 64){
        int m = (k >= 1000) ? 2 : ((k >= 500) ? 1 : 0);
        int kk = k - m*500;
        int prow = (m == 0) ? p0 : (m == 1) ? p1 : p2;
        float f = fmaxf(b2f(hT[(size_t)kk*LDR + prow]), 0.f);
        #pragma unroll
        for (int c = 0; c < 7; ++c) acc[c] += f * Wfc[(size_t)k*7 + c];
    }
    #pragma unroll
    for (int off = 32; off > 0; off >>= 1){
        #pragma unroll
        for (int c = 0; c < 7; ++c) acc[c] += __shfl_down(acc[c], off, 64);
    }
    if (lane == 0){
        float lg[7], mx = -1e30f;
        #pragma unroll
        for (int c = 0; c < 7; ++c){ lg[c] = acc[c] + bfc[c]; mx = fmaxf(mx, lg[c]); }
        float s = 0.f;
        #pragma unroll
        for (int c = 0; c < 7; ++c) s += expf(lg[c] - mx);
        float lse = mx + logf(s);
        #pragma unroll
        for (int c = 0; c < 7; ++c) out[(size_t)i*7 + c] = lg[c] - lse;
    }
}

extern "C" void kernel_launch(void* const* d_in, const int* in_sizes, int n_in,
                              void* d_out, int out_size, void* d_ws, size_t ws_size,
                              hipStream_t stream)
{
    const float* speaker = (const float*)d_in[1];
    const float* fea_a   = (const float*)d_in[2];
    const float* fea_v   = (const float*)d_in[3];
    const float* fea_t   = (const float*)d_in[4];
    const float* Wa      = (const float*)d_in[5];
    const float* ba      = (const float*)d_in[6];
    const float* Wv      = (const float*)d_in[7];
    const float* bv      = (const float*)d_in[8];
    const float* Wt_in   = (const float*)d_in[9];
    const float* bt      = (const float*)d_in[10];
    const float* spk_emb = (const float*)d_in[11];
    const float* W_in    = (const float*)d_in[12];
    const float* b_in    = (const float*)d_in[13];
    const float* W_convs = (const float*)d_in[14];
    const float* W_fc1   = (const float*)d_in[15];
    const float* b_fc1   = (const float*)d_in[16];
    const int* seq = (const int*)d_in[18];
    const int* bat = (const int*)d_in[19];
    const int* dia = (const int*)d_in[20];

    const int N  = in_sizes[18];   // 411
    const int M3 = 3*N;            // 1233

    char* wsb = (char*)d_ws;
    float* A     = (float*)(wsb + 0);             // 1344*1344*4 = 7,225,344
    us*    Abf   = (us*)   (wsb + 8388608);       // 3,612,672
    float* x     = (float*)(wsb + 12582912);
    float* fn    = (float*)(wsb + 14680064);
    float* h0    = (float*)(wsb + 16777216);
    us*    h0b   = (us*)   (wsb + 19922944);
    us*    h0bT  = (us*)   (wsb + 21495808);      // 512*1344*2
    us*    hTa   = (us*)   (wsb + 23068672);
    us*    hTb   = (us*)   (wsb + 24641536);
    us*    Wt    = (us*)   (wsb + 33554432);      // 64*512*1024*2 = 67,108,864
    float* dinv  = (float*)(wsb + 100663296);
    int*   off13 = (int*)  (wsb + 100669440);
    int*   rmap3 = (int*)  (wsb + 100670464);
    int*   tileK = (int*)  (wsb + 100676608);
    int*   spki  = (int*)  (wsb + 100853760);
    float* xga   = (float*)(wsb + 100859904);
    float* xgv   = (float*)(wsb + 103727104);
    float* xgt   = (float*)(wsb + 104415232);
    float* WaT   = (float*)(wsb + 106250240);
    float* WvT   = (float*)(wsb + 108170240);
    float* WtT   = (float*)(wsb + 108631040);
    float* xpa   = (float*)(wsb + 109859840);
    float* xpv   = (float*)(wsb + 112153600);
    float* xpt   = (float*)(wsb + 113300480);

    hipMemsetAsync(A,    0, 7225344, stream);
    hipMemsetAsync(Abf,  0, 3612672, stream);
    hipMemsetAsync(x,    0, 1638400, stream);
    hipMemsetAsync(fn,   0, 1638400, stream);
    hipMemsetAsync(h0bT, 0, 1376256, stream);
    hipMemsetAsync(hTa,  0, 1376256, stream);
    hipMemsetAsync(hTb,  0, 1376256, stream);

    k_offsets<<<1, 64, 0, stream>>>(dia, N, off13, rmap3, tileK);
    k_gather<<<448, 256, 0, stream>>>(fea_a, fea_v, fea_t, speaker, seq, bat, xga, xgv, xgt, spki, N);

    k_trw<<<dim3(25, 5), 256, 0, stream>>>(Wa,    1582, 1600, WaT);
    k_trw<<<dim3( 6, 5), 256, 0, stream>>>(Wv,     342,  384, WvT);
    k_trw<<<dim3(16, 5), 256, 0, stream>>>(Wt_in, 1024, 1024, WtT);

    k_projg2<<<dim3(5, 7, 4), 256, 0, stream>>>(xga, 1600, 400, WaT, xpa);
    k_projg2<<<dim3(5, 7, 2), 256, 0, stream>>>(xgv,  384, 192, WvT, xpv);
    k_projg2<<<dim3(5, 7, 4), 256, 0, stream>>>(xgt, 1024, 256, WtT, xpt);

    k_norm2<<<M3, 256, 0, stream>>>(xpa, xpv, xpt, ba, bv, bt, spk_emb, spki, rmap3, x, fn, N);

    int nt = (N + 31)/32;
    k_intra<<<dim3(nt, nt, 3), dim3(16,16), 0, stream>>>(fn, dia, rmap3, A, N);
    k_cross<<<N, 64, 0, stream>>>(fn, rmap3, A, N);
    k_rowsum<<<M3, 256, 0, stream>>>(A, dinv, M3);
    k_scale<<<dim3(78, 78), dim3(16,16), 0, stream>>>(A, Abf, dinv, M3);

    k_gemm_h0<<<dim3(8, 20), 256, 0, stream>>>(x, W_in, b_in, h0, h0b, h0bT, M3);
    k_wtr<<<dim3(16, 8, 64), 256, 0, stream>>>(W_convs, Wt);

    const us* srcp = h0bT;
    for (int l = 1; l <= 64; ++l){
        us* dstp = ((l-1) & 1) ? hTb : hTa;
        float thv = logf(0.5f/(float)l + 1.0f);
        k_layer5<<<160, 512, 0, stream>>>(Abf, srcp, h0, h0b,
                                          Wt + (size_t)(l-1)*LDH*1024, tileK, thv, dstp);
        srcp = dstp;
    }

    k_final<<<N, 64, 0, stream>>>(hTb, W_fc1, b_fc1, rmap3, (float*)d_out, N);
}

// Round 10
// 1897.320 us; speedup vs baseline: 1.5087x; 1.3741x over previous
//
#include <hip/hip_runtime.h>
#include <hip/hip_bf16.h>
#include <math.h>

#define LDAB 1344  // A_perm col stride (1233 -> 1344)
#define LDR  1344  // hT row capacity
#define LDH  512   // padded G (500 -> 512)
#define LDX  320   // padded H (300 -> 320)

typedef __attribute__((ext_vector_type(8))) short short8;
typedef __attribute__((ext_vector_type(4))) float f32x4;
typedef unsigned short us;

__device__ __forceinline__ us f2b(float x){
    unsigned int u = __float_as_uint(x);
    return (us)((u + 0x7fffu + ((u >> 16) & 1u)) >> 16);
}
__device__ __forceinline__ float b2f(us u){ return __uint_as_float(((unsigned int)u) << 16); }

__device__ __forceinline__ float arc_sim(float c){
    float cc = fminf(1.f, fmaxf(-1.f, c * 0.99999f));
    return 1.f - acosf(cc) * 0.31830988618379067f;
}

#define SWZ(r, k)    (((r)*64  + (k)) ^ (((r)&7)<<3))
#define SWZ128(r, k) ((r)*128 + ((k) ^ (((r)&7)<<3)))

// ---------------- offsets / permutation map / tile bands ----------------
__global__ void k_offsets(const int* __restrict__ dia, int N,
                          int* __restrict__ off13, int* __restrict__ rmap3, int* __restrict__ tileK)
{
    __shared__ int soff[13], slen[12];
    if (threadIdx.x == 0){
        int d = 0; soff[0] = 0;
        for (int i = 0; i < N; ++i){
            while (dia[i] > d){ ++d; soff[d] = i; }
        }
        for (int dd = d+1; dd <= 12; ++dd) soff[dd] = N;
        for (int dd = 0; dd < 12; ++dd) slen[dd] = soff[dd+1] - soff[dd];
        for (int dd = 0; dd < 13; ++dd) off13[dd] = soff[dd];
    }
    __syncthreads();
    for (int i = threadIdx.x; i < N; i += 64){
        int d = dia[i];
        int base = 3*soff[d], u = i - soff[d], l = slen[d];
        rmap3[0*448 + i] = base + u;
        rmap3[1*448 + i] = base + l + u;
        rmap3[2*448 + i] = base + 2*l + u;
    }
    if (threadIdx.x < 20){
        int it = threadIdx.x;
        int r0 = it*64, r1 = min(it*64 + 63, 3*N - 1);
        int dfirst = 11, dlast = 11;
        for (int dd = 0; dd < 12; ++dd){ if (r0 < 3*soff[dd+1]){ dfirst = dd; break; } }
        for (int dd = 0; dd < 12; ++dd){ if (r1 < 3*soff[dd+1]){ dlast = dd; break; } }
        tileK[it]      = (3*soff[dfirst]) & ~63;       // 64-aligned band start
        tileK[20 + it] = 3*soff[dlast] + 3*slen[dlast];
    }
}

// ---------------- gather ragged utterances into padded buffers + speaker idx ----------------
__global__ __launch_bounds__(256)
void k_gather(const float* __restrict__ fa, const float* __restrict__ fv, const float* __restrict__ ft,
              const float* __restrict__ speaker, const int* __restrict__ seq, const int* __restrict__ bat,
              float* __restrict__ xga, float* __restrict__ xgv, float* __restrict__ xgt,
              int* __restrict__ spki, int N)
{
    int i = blockIdx.x;
    int tid = threadIdx.x;
    bool real = i < N;
    int s = real ? seq[i] : 0, b = real ? bat[i] : 0;
    size_t base = (size_t)(s*12 + b);
    for (int k = tid; k < 1600; k += 256) xga[(size_t)i*1600 + k] = (real && k < 1582) ? fa[base*1582 + k] : 0.f;
    for (int k = tid; k < 384;  k += 256) xgv[(size_t)i*384  + k] = (real && k < 342)  ? fv[base*342  + k] : 0.f;
    for (int k = tid; k < 1024; k += 256) xgt[(size_t)i*1024 + k] = real ? ft[base*1024 + k] : 0.f;
    if (tid == 0){
        int bi = 0;
        if (real){
            const float* sp = speaker + base*9;
            float best = sp[0];
            for (int c = 1; c < 9; ++c) if (sp[c] > best){ best = sp[c]; bi = c; }
        }
        spki[i] = bi;
    }
}

// ---------------- transpose projection weight W[D][300] -> WT[300][Kp] fp32 ----------------
__global__ __launch_bounds__(256)
void k_trw(const float* __restrict__ W, int D, int Kp, float* __restrict__ WTr)
{
    __shared__ float tt[64][65];
    int k0 = blockIdx.x*64, j0 = blockIdx.y*64;
    int t = threadIdx.x;
    #pragma unroll
    for (int rr = 0; rr < 4; ++rr){
        int kl = (t >> 4) + rr*16;
        int k  = k0 + kl;
        int jl = (t & 15) * 4;
        int j  = j0 + jl;
        float4 v;
        if (k < D && j + 3 < 300){
            v = *(const float4*)&W[(size_t)k*300 + j];
        } else {
            v.x = (k < D && j+0 < 300) ? W[(size_t)k*300 + j+0] : 0.f;
            v.y = (k < D && j+1 < 300) ? W[(size_t)k*300 + j+1] : 0.f;
            v.z = (k < D && j+2 < 300) ? W[(size_t)k*300 + j+2] : 0.f;
            v.w = (k < D && j+3 < 300) ? W[(size_t)k*300 + j+3] : 0.f;
        }
        tt[jl+0][kl] = v.x; tt[jl+1][kl] = v.y; tt[jl+2][kl] = v.z; tt[jl+3][kl] = v.w;
    }
    __syncthreads();
    #pragma unroll
    for (int rr = 0; rr < 4; ++rr){
        int jl = (t >> 4) + rr*16;
        int j  = j0 + jl;
        int kq = (t & 15) * 4;
        if (j < 300){
            float4 o; o.x = tt[jl][kq]; o.y = tt[jl][kq+1]; o.z = tt[jl][kq+2]; o.w = tt[jl][kq+3];
            *(float4*)&WTr[(size_t)j*Kp + k0 + kq] = o;
        }
    }
}

// ---------------- projection GEMM partials (split-K) ----------------
__global__ __launch_bounds__(256)
void k_projg2(const float* __restrict__ xg, int Kp, int kslice,
              const float* __restrict__ WTr, float* __restrict__ xp)
{
    __shared__ float As[16][68];
    __shared__ float Bs[16][64];
    int i0 = blockIdx.y*64, j0 = blockIdx.x*64;
    int ks0 = blockIdx.z * kslice;
    int tid = threadIdx.x;
    int ty = tid >> 4, tx = tid & 15;
    int lr = tid >> 2, lk = (tid & 3) << 2;
    int bj = tid & 63, bk4 = (tid >> 6) << 2;
    float acc[4][4] = {};
    for (int k0 = 0; k0 < kslice; k0 += 16){
        float4 av = *(const float4*)&xg[(size_t)(i0+lr)*Kp + ks0 + k0 + lk];
        float4 wv = {0.f, 0.f, 0.f, 0.f};
        int j = j0 + bj;
        if (j < 300) wv = *(const float4*)&WTr[(size_t)j*Kp + ks0 + k0 + bk4];
        __syncthreads();
        As[lk+0][lr] = av.x; As[lk+1][lr] = av.y; As[lk+2][lr] = av.z; As[lk+3][lr] = av.w;
        Bs[bk4+0][bj] = wv.x; Bs[bk4+1][bj] = wv.y; Bs[bk4+2][bj] = wv.z; Bs[bk4+3][bj] = wv.w;
        __syncthreads();
        #pragma unroll
        for (int kk = 0; kk < 16; ++kk){
            float4 a4 = *(const float4*)&As[kk][ty*4];
            float4 b4 = *(const float4*)&Bs[kk][tx*4];
            float a_[4] = {a4.x, a4.y, a4.z, a4.w};
            float b_[4] = {b4.x, b4.y, b4.z, b4.w};
            #pragma unroll
            for (int u = 0; u < 4; ++u)
                #pragma unroll
                for (int v = 0; v < 4; ++v) acc[u][v] += a_[u]*b_[v];
        }
    }
    #pragma unroll
    for (int u = 0; u < 4; ++u){
        int i = i0 + ty*4 + u;
        #pragma unroll
        for (int v = 0; v < 4; ++v)
            xp[((size_t)blockIdx.z*448 + i)*320 + j0 + tx*4 + v] = acc[u][v];
    }
}

// ---------------- reduce split-K + bias + spk -> x (PERMUTED rows) and fn ----------------
__global__ __launch_bounds__(256)
void k_norm2(const float* __restrict__ xpa, const float* __restrict__ xpv, const float* __restrict__ xpt,
             const float* __restrict__ ba, const float* __restrict__ bv, const float* __restrict__ bt,
             const float* __restrict__ spk_emb, const int* __restrict__ spki,
             const int* __restrict__ rmap3,
             float* __restrict__ x, float* __restrict__ fn, int N)
{
    __shared__ float red[4];
    int r = blockIdx.x, tid = threadIdx.x;
    int m = (r >= 2*N) ? 2 : (r >= N ? 1 : 0);
    int n = r - m*N;
    const float* xp   = (m==0) ? xpa : (m==1) ? xpv : xpt;
    const float* bias = (m==0) ? ba  : (m==1) ? bv  : bt;
    int KS = (m==1) ? 2 : 4;
    float v0 = 0.f, v1 = 0.f;
    int j0 = tid, j1 = tid + 256;
    if (j0 < 300){
        float s = bias[j0];
        for (int si = 0; si < KS; ++si) s += xp[((size_t)si*448 + n)*320 + j0];
        if (m == 2) s += spk_emb[spki[n]*300 + j0];
        v0 = s;
    }
    if (j1 < 300){
        float s = bias[j1];
        for (int si = 0; si < KS; ++si) s += xp[((size_t)si*448 + n)*320 + j1];
        if (m == 2) s += spk_emb[spki[n]*300 + j1];
        v1 = s;
    }
    float ss = v0*v0 + v1*v1;
    #pragma unroll
    for (int off = 32; off > 0; off >>= 1) ss += __shfl_down(ss, off, 64);
    if ((tid & 63) == 0) red[tid >> 6] = ss;
    __syncthreads();
    float tot = red[0] + red[1] + red[2] + red[3];
    float inv = 1.f / (sqrtf(tot) + 1e-8f);
    int prow = rmap3[m*448 + n];
    x [(size_t)prow*LDX + j0] = v0;
    fn[(size_t)r*LDX + j0] = v0 * inv;
    if (j1 < 320){
        x [(size_t)prow*LDX + j1] = v1;
        fn[(size_t)r*LDX + j1] = v1 * inv;
    }
}

// ---------------- intra-modal adjacency -> PERMUTED block-diagonal A ----------------
__global__ __launch_bounds__(256)
void k_intra(const float* __restrict__ fn, const int* __restrict__ dia,
             const int* __restrict__ rmap3, float* __restrict__ A, int N)
{
    int m  = blockIdx.z;
    int i0 = blockIdx.y * 32, j0 = blockIdx.x * 32;
    int iend = min(i0 + 31, N - 1), jend = min(j0 + 31, N - 1);
    if (dia[iend] < dia[j0] || dia[jend] < dia[i0]) return;

    __shared__ float As[32][17], Bs[32][17];
    int tx = threadIdx.x, ty = threadIdx.y;
    int tid = ty*16 + tx;
    float acc[2][2] = {};
    for (int k0 = 0; k0 < 320; k0 += 16){
        __syncthreads();
        for (int l = tid; l < 512; l += 256){
            int r = l >> 4, kk = l & 15;
            int gi = i0 + r, gj = j0 + r;
            As[r][kk] = (gi < N) ? fn[((size_t)m*N + gi)*LDX + k0 + kk] : 0.f;
            Bs[r][kk] = (gj < N) ? fn[((size_t)m*N + gj)*LDX + k0 + kk] : 0.f;
        }
        __syncthreads();
        #pragma unroll
        for (int kk = 0; kk < 16; ++kk){
            float a0 = As[ty*2+0][kk], a1 = As[ty*2+1][kk];
            float b0 = Bs[tx*2+0][kk], b1 = Bs[tx*2+1][kk];
            acc[0][0] += a0*b0; acc[0][1] += a0*b1;
            acc[1][0] += a1*b0; acc[1][1] += a1*b1;
        }
    }
    #pragma unroll
    for (int u = 0; u < 2; ++u)
        #pragma unroll
        for (int v = 0; v < 2; ++v){
            int i = i0 + ty*2 + u, j = j0 + tx*2 + v;
            if (i < N && j < N && dia[i] == dia[j]){
                int pi = rmap3[m*448 + i], pj = rmap3[m*448 + j];
                A[(size_t)pi*LDAB + pj] = arc_sim(acc[u][v]);
            }
        }
}

// ---------------- cross-modal diagonal links (permuted) ----------------
__global__ void k_cross(const float* __restrict__ fn, const int* __restrict__ rmap3,
                        float* __restrict__ A, int N)
{
    int i = blockIdx.x, lane = threadIdx.x;
    float d01 = 0.f, d02 = 0.f, d12 = 0.f;
    for (int k = lane; k < 300; k += 64){
        float a = fn[((size_t)0*N + i)*LDX + k];
        float b = fn[((size_t)1*N + i)*LDX + k];
        float c = fn[((size_t)2*N + i)*LDX + k];
        d01 += a*b; d02 += a*c; d12 += b*c;
    }
    #pragma unroll
    for (int off = 32; off > 0; off >>= 1){
        d01 += __shfl_down(d01, off, 64);
        d02 += __shfl_down(d02, off, 64);
        d12 += __shfl_down(d12, off, 64);
    }
    if (lane == 0){
        float s01 = arc_sim(d01), s02 = arc_sim(d02), s12 = arc_sim(d12);
        size_t p0 = rmap3[i], p1 = rmap3[448 + i], p2 = rmap3[896 + i];
        A[p0*LDAB + p1] = s01; A[p1*LDAB + p0] = s01;
        A[p0*LDAB + p2] = s02; A[p2*LDAB + p0] = s02;
        A[p1*LDAB + p2] = s12; A[p2*LDAB + p1] = s12;
    }
}

// ---------------- degree + D^-1/2 ----------------
__global__ __launch_bounds__(256)
void k_rowsum(const float* __restrict__ A, float* __restrict__ dinv, int M3)
{
    __shared__ float red[4];
    int r = blockIdx.x, tid = threadIdx.x;
    float s = 0.f;
    for (int c = tid; c < LDAB; c += 256) s += A[(size_t)r*LDAB + c];
    #pragma unroll
    for (int off = 32; off > 0; off >>= 1) s += __shfl_down(s, off, 64);
    if ((tid & 63) == 0) red[tid >> 6] = s;
    __syncthreads();
    if (tid == 0){
        float tot = red[0] + red[1] + red[2] + red[3];
        dinv[r] = (tot > 0.f) ? 1.f / sqrtf(tot) : 0.f;
    }
}

// ---------------- scale + bf16 copy ----------------
__global__ void k_scale(float* __restrict__ A, us* __restrict__ Abf,
                        const float* __restrict__ dinv, int M3)
{
    int c = blockIdx.x*16 + threadIdx.x;
    int r = blockIdx.y*16 + threadIdx.y;
    if (r < M3 && c < M3){
        float v = A[(size_t)r*LDAB + c] * dinv[r]*dinv[c];
        A[(size_t)r*LDAB + c] = v;
        Abf[(size_t)r*LDAB + c] = f2b(v);
    }
}

// ---------------- h0 = relu(x @ W_in + b_in) (permuted rows) ----------------
__global__ __launch_bounds__(256)
void k_gemm_h0(const float* __restrict__ x, const float* __restrict__ Win,
               const float* __restrict__ bin, float* __restrict__ h0,
               us* __restrict__ h0b, us* __restrict__ h0bT, int M3)
{
    __shared__ float As[16][68];
    __shared__ float Bs[16][64];
    int i0 = blockIdx.y*64, j0 = blockIdx.x*64;
    int tid = threadIdx.x;
    int ty = tid >> 4, tx = tid & 15;
    int lr = tid >> 2, lk = (tid & 3) << 2;
    int br = tid >> 4, bc = (tid & 15) << 2;
    float acc[4][4] = {};
    for (int k0 = 0; k0 < 320; k0 += 16){
        float4 av = *(const float4*)&x[(size_t)(i0+lr)*LDX + k0 + lk];
        float4 bwv;
        {
            int kr = k0 + br;
            int c0 = j0 + bc;
            if (kr < 300 && c0 + 3 < 500){
                bwv = *(const float4*)&Win[(size_t)kr*500 + c0];
            } else {
                bwv.x = (kr < 300 && c0+0 < 500) ? Win[(size_t)kr*500 + c0+0] : 0.f;
                bwv.y = (kr < 300 && c0+1 < 500) ? Win[(size_t)kr*500 + c0+1] : 0.f;
                bwv.z = (kr < 300 && c0+2 < 500) ? Win[(size_t)kr*500 + c0+2] : 0.f;
                bwv.w = (kr < 300 && c0+3 < 500) ? Win[(size_t)kr*500 + c0+3] : 0.f;
            }
        }
        __syncthreads();
        As[lk+0][lr] = av.x; As[lk+1][lr] = av.y; As[lk+2][lr] = av.z; As[lk+3][lr] = av.w;
        *(float4*)&Bs[br][bc] = bwv;
        __syncthreads();
        #pragma unroll
        for (int kk = 0; kk < 16; ++kk){
            float4 a4 = *(const float4*)&As[kk][ty*4];
            float4 b4 = *(const float4*)&Bs[kk][tx*4];
            float a_[4] = {a4.x, a4.y, a4.z, a4.w};
            float b_[4] = {b4.x, b4.y, b4.z, b4.w};
            #pragma unroll
            for (int u = 0; u < 4; ++u)
                #pragma unroll
                for (int v = 0; v < 4; ++v) acc[u][v] += a_[u]*b_[v];
        }
    }
    #pragma unroll
    for (int u = 0; u < 4; ++u){
        int i = i0 + ty*4 + u;
        #pragma unroll
        for (int v = 0; v < 4; ++v){
            int j = j0 + tx*4 + v;
            float val = 0.f;
            if (i < M3 && j < 500) val = fmaxf(acc[u][v] + bin[j], 0.f);
            h0[(size_t)i*LDH + j] = val;
            us bv = f2b(val);
            h0b[(size_t)i*LDH + j] = bv;
            h0bT[(size_t)j*LDR + i] = bv;
        }
    }
}

// ---------------- convert ALL 64 layers of W to bf16 transposed ----------------
__global__ __launch_bounds__(256)
void k_wtr(const float* __restrict__ Wc, us* __restrict__ Wt)
{
    __shared__ us sT[64][72];
    int l = blockIdx.z;
    int k0 = blockIdx.x*64, j0 = blockIdx.y*64;
    const float* W = Wc + (size_t)l*500000;
    int ksrc0 = (k0 < 512) ? k0 : k0 - 12;
    int klim  = (k0 < 512) ? 500 : 1000;
    int t = threadIdx.x;
    #pragma unroll
    for (int rr = 0; rr < 4; ++rr){
        int kl = (t >> 4) + rr*16;
        int k  = ksrc0 + kl;
        int jl = (t & 15) * 4;
        int j  = j0 + jl;
        bool vk = (k < klim);
        float4 v;
        if (vk && j + 3 < 500){
            v = *(const float4*)&W[(size_t)k*500 + j];
        } else {
            v.x = (vk && j+0 < 500) ? W[(size_t)k*500 + j+0] : 0.f;
            v.y = (vk && j+1 < 500) ? W[(size_t)k*500 + j+1] : 0.f;
            v.z = (vk && j+2 < 500) ? W[(size_t)k*500 + j+2] : 0.f;
            v.w = (vk && j+3 < 500) ? W[(size_t)k*500 + j+3] : 0.f;
        }
        sT[jl+0][kl] = f2b(v.x);
        sT[jl+1][kl] = f2b(v.y);
        sT[jl+2][kl] = f2b(v.z);
        sT[jl+3][kl] = f2b(v.w);
    }
    __syncthreads();
    int jl = t >> 2, kc = (t & 3) * 16;
    us* dst = Wt + (size_t)l*LDH*1024 + (size_t)(j0+jl)*1024 + k0 + kc;
    *(uint4*)&dst[0] = *(const uint4*)&sT[jl][kc];
    *(uint4*)&dst[8] = *(const uint4*)&sT[jl][kc+8];
}

// ---------------- GEMM1 (MFMA, reg-prefetch, BANDED K): hi = A @ h ----------------
__global__ __launch_bounds__(256)
void k_spmm(const us* __restrict__ Abf, const us* __restrict__ hT,
            const int* __restrict__ tileK,
            float* __restrict__ hi, us* __restrict__ hib)
{
    __shared__ us sA[64*64], sB[64*64];
    const int i0 = blockIdx.y*64, j0 = blockIdx.x*64;
    const int tid = threadIdx.x, lane = tid & 63, w = tid >> 6;
    const int wr = w >> 1, wc = w & 1;
    const int srow = tid >> 2, scol = (tid & 3) * 16;
    const int kminf = tileK[blockIdx.y];
    const int kmax  = tileK[20 + blockIdx.y];
    const int T = (kmax - kminf + 63) >> 6;
    const us* pa = &Abf[(size_t)(i0+srow)*LDAB + kminf + scol];
    const us* pb = &hT [(size_t)(j0+srow)*LDR  + kminf + scol];
    uint4 a0 = *(const uint4*)(pa);
    uint4 a1 = *(const uint4*)(pa + 8);
    uint4 b0 = *(const uint4*)(pb);
    uint4 b1 = *(const uint4*)(pb + 8);
    f32x4 acc[2][2] = {};
    for (int t = 0; t < T; ++t){
        *(uint4*)&sA[SWZ(srow, scol)]     = a0;
        *(uint4*)&sA[SWZ(srow, scol + 8)] = a1;
        *(uint4*)&sB[SWZ(srow, scol)]     = b0;
        *(uint4*)&sB[SWZ(srow, scol + 8)] = b1;
        if (t + 1 < T){
            int ko = (t+1)*64;
            a0 = *(const uint4*)(pa + ko);
            a1 = *(const uint4*)(pa + ko + 8);
            b0 = *(const uint4*)(pb + ko);
            b1 = *(const uint4*)(pb + ko + 8);
        }
        __syncthreads();
        #pragma unroll
        for (int ks = 0; ks < 2; ++ks){
            int kk = ks*32 + (lane >> 4)*8;
            short8 af[2], bfr[2];
            #pragma unroll
            for (int fr = 0; fr < 2; ++fr)
                af[fr] = *(const short8*)&sA[SWZ(wr*32 + fr*16 + (lane & 15), kk)];
            #pragma unroll
            for (int fc = 0; fc < 2; ++fc)
                bfr[fc] = *(const short8*)&sB[SWZ(wc*32 + fc*16 + (lane & 15), kk)];
            #pragma unroll
            for (int fr = 0; fr < 2; ++fr)
                #pragma unroll
                for (int fc = 0; fc < 2; ++fc)
                    acc[fr][fc] = __builtin_amdgcn_mfma_f32_16x16x32_bf16(af[fr], bfr[fc], acc[fr][fc], 0, 0, 0);
        }
        __syncthreads();
    }
    #pragma unroll
    for (int fr = 0; fr < 2; ++fr)
        #pragma unroll
        for (int fc = 0; fc < 2; ++fc)
            #pragma unroll
            for (int rg = 0; rg < 4; ++rg){
                int i = i0 + wr*32 + fr*16 + (lane >> 4)*4 + rg;
                int j = j0 + wc*32 + fc*16 + (lane & 15);
                float v = acc[fr][fc][rg];
                hi [(size_t)i*LDH + j] = v;
                hib[(size_t)i*LDH + j] = f2b(v);
            }
}

// ---------------- GEMM2 (MFMA, BK=128, reg-prefetch) + GCNII epilogue ----------------
__global__ __launch_bounds__(256)
void k_layerm(const us* __restrict__ hib, const us* __restrict__ h0b,
              const us* __restrict__ Wt, const float* __restrict__ hi,
              const float* __restrict__ h0, float theta, float cth,
              us* __restrict__ hT_out)
{
    __shared__ us sA[64*128], sB[64*128];   // 16 KB + 16 KB
    const int i0 = blockIdx.y*64, j0 = blockIdx.x*64;
    const int tid = threadIdx.x, lane = tid & 63, w = tid >> 6;
    const int wr = w >> 1, wc = w & 1;
    const int srow = tid >> 2, scol = (tid & 3) * 32;
    const us* paA = &hib[(size_t)(i0+srow)*LDH + scol];
    const us* paB = &h0b[(size_t)(i0+srow)*LDH + scol];
    const us* pw  = &Wt [(size_t)(j0+srow)*1024 + scol];
    uint4 a[4], b[4];
    #pragma unroll
    for (int q = 0; q < 4; ++q){
        a[q] = *(const uint4*)(paA + q*8);
        b[q] = *(const uint4*)(pw  + q*8);
    }
    f32x4 acc[2][2] = {};
    for (int t = 0; t < 8; ++t){
        #pragma unroll
        for (int q = 0; q < 4; ++q){
            *(uint4*)&sA[SWZ128(srow, scol + q*8)] = a[q];
            *(uint4*)&sB[SWZ128(srow, scol + q*8)] = b[q];
        }
        if (t + 1 < 8){
            int kn = (t+1)*128;
            const us* ap = (kn < 512) ? (paA + kn) : (paB + kn - 512);
            #pragma unroll
            for (int q = 0; q < 4; ++q){
                a[q] = *(const uint4*)(ap + q*8);
                b[q] = *(const uint4*)(pw + kn + q*8);
            }
        }
        __syncthreads();
        #pragma unroll
        for (int ks = 0; ks < 4; ++ks){
            int kk = ks*32 + (lane >> 4)*8;
            short8 af[2], bfr[2];
            #pragma unroll
            for (int fr = 0; fr < 2; ++fr)
                af[fr] = *(const short8*)&sA[SWZ128(wr*32 + fr*16 + (lane & 15), kk)];
            #pragma unroll
            for (int fc = 0; fc < 2; ++fc)
                bfr[fc] = *(const short8*)&sB[SWZ128(wc*32 + fc*16 + (lane & 15), kk)];
            #pragma unroll
            for (int fr = 0; fr < 2; ++fr)
                #pragma unroll
                for (int fc = 0; fc < 2; ++fc)
                    acc[fr][fc] = __builtin_amdgcn_mfma_f32_16x16x32_bf16(af[fr], bfr[fc], acc[fr][fc], 0, 0, 0);
        }
        __syncthreads();
    }
    #pragma unroll
    for (int fr = 0; fr < 2; ++fr)
        #pragma unroll
        for (int fc = 0; fc < 2; ++fc)
            #pragma unroll
            for (int rg = 0; rg < 4; ++rg){
                int i = i0 + wr*32 + fr*16 + (lane >> 4)*4 + rg;
                int j = j0 + wc*32 + fc*16 + (lane & 15);
                float hv  = hi[(size_t)i*LDH + j];
                float h0v = h0[(size_t)i*LDH + j];
                float o = fmaxf(theta*acc[fr][fc][rg] + cth*(0.9f*hv + 0.1f*h0v), 0.f);
                hT_out[(size_t)j*LDR + i] = f2b(o);
            }
}

// ---------------- final classify + log_softmax ----------------
__global__ void k_final(const us* __restrict__ hT, const float* __restrict__ Wfc,
                        const float* __restrict__ bfc, const int* __restrict__ rmap3,
                        float* __restrict__ out, int N)
{
    int i = blockIdx.x, lane = threadIdx.x;
    int p0 = rmap3[i], p1 = rmap3[448 + i], p2 = rmap3[896 + i];
    float acc[7] = {};
    for (int k = lane; k < 1500; k += 64){
        int m = (k >= 1000) ? 2 : ((k >= 500) ? 1 : 0);
        int kk = k - m*500;
        int prow = (m == 0) ? p0 : (m == 1) ? p1 : p2;
        float f = fmaxf(b2f(hT[(size_t)kk*LDR + prow]), 0.f);
        #pragma unroll
        for (int c = 0; c < 7; ++c) acc[c] += f * Wfc[(size_t)k*7 + c];
    }
    #pragma unroll
    for (int off = 32; off > 0; off >>= 1){
        #pragma unroll
        for (int c = 0; c < 7; ++c) acc[c] += __shfl_down(acc[c], off, 64);
    }
    if (lane == 0){
        float lg[7], mx = -1e30f;
        #pragma unroll
        for (int c = 0; c < 7; ++c){ lg[c] = acc[c] + bfc[c]; mx = fmaxf(mx, lg[c]); }
        float s = 0.f;
        #pragma unroll
        for (int c = 0; c < 7; ++c) s += expf(lg[c] - mx);
        float lse = mx + logf(s);
        #pragma unroll
        for (int c = 0; c < 7; ++c) out[(size_t)i*7 + c] = lg[c] - lse;
    }
}

extern "C" void kernel_launch(void* const* d_in, const int* in_sizes, int n_in,
                              void* d_out, int out_size, void* d_ws, size_t ws_size,
                              hipStream_t stream)
{
    const float* speaker = (const float*)d_in[1];
    const float* fea_a   = (const float*)d_in[2];
    const float* fea_v   = (const float*)d_in[3];
    const float* fea_t   = (const float*)d_in[4];
    const float* Wa      = (const float*)d_in[5];
    const float* ba      = (const float*)d_in[6];
    const float* Wv      = (const float*)d_in[7];
    const float* bv      = (const float*)d_in[8];
    const float* Wt_in   = (const float*)d_in[9];
    const float* bt      = (const float*)d_in[10];
    const float* spk_emb = (const float*)d_in[11];
    const float* W_in    = (const float*)d_in[12];
    const float* b_in    = (const float*)d_in[13];
    const float* W_convs = (const float*)d_in[14];
    const float* W_fc1   = (const float*)d_in[15];
    const float* b_fc1   = (const float*)d_in[16];
    const int* seq = (const int*)d_in[18];
    const int* bat = (const int*)d_in[19];
    const int* dia = (const int*)d_in[20];

    const int N  = in_sizes[18];   // 411
    const int M3 = 3*N;            // 1233

    char* wsb = (char*)d_ws;
    float* A     = (float*)(wsb + 0);             // 1344*1344*4 = 7,225,344
    us*    Abf   = (us*)   (wsb + 8388608);       // 3,612,672
    float* x     = (float*)(wsb + 12582912);
    float* fn    = (float*)(wsb + 14680064);
    float* h0    = (float*)(wsb + 16777216);
    us*    h0b   = (us*)   (wsb + 19922944);
    us*    h0bT  = (us*)   (wsb + 21495808);      // 512*1344*2
    us*    hTa   = (us*)   (wsb + 23068672);
    us*    hTb   = (us*)   (wsb + 24641536);
    float* hi    = (float*)(wsb + 26214400);      // 1280*512*4 = 2,621,440
    us*    hib   = (us*)   (wsb + 28835840);      // 1280*512*2 = 1,310,720
    us*    Wt    = (us*)   (wsb + 33554432);      // 64*512*1024*2 = 67,108,864
    float* dinv  = (float*)(wsb + 100663296);
    int*   off13 = (int*)  (wsb + 100669440);
    int*   rmap3 = (int*)  (wsb + 100670464);
    int*   tileK = (int*)  (wsb + 100676608);
    int*   spki  = (int*)  (wsb + 100853760);
    float* xga   = (float*)(wsb + 100859904);
    float* xgv   = (float*)(wsb + 103727104);
    float* xgt   = (float*)(wsb + 104415232);
    float* WaT   = (float*)(wsb + 106250240);
    float* WvT   = (float*)(wsb + 108170240);
    float* WtT   = (float*)(wsb + 108631040);
    float* xpa   = (float*)(wsb + 109859840);
    float* xpv   = (float*)(wsb + 112153600);
    float* xpt   = (float*)(wsb + 113300480);

    hipMemsetAsync(A,    0, 7225344, stream);
    hipMemsetAsync(Abf,  0, 3612672, stream);
    hipMemsetAsync(x,    0, 1638400, stream);
    hipMemsetAsync(fn,   0, 1638400, stream);
    hipMemsetAsync(h0bT, 0, 1376256, stream);
    hipMemsetAsync(hTa,  0, 1376256, stream);
    hipMemsetAsync(hTb,  0, 1376256, stream);

    k_offsets<<<1, 64, 0, stream>>>(dia, N, off13, rmap3, tileK);
    k_gather<<<448, 256, 0, stream>>>(fea_a, fea_v, fea_t, speaker, seq, bat, xga, xgv, xgt, spki, N);

    k_trw<<<dim3(25, 5), 256, 0, stream>>>(Wa,    1582, 1600, WaT);
    k_trw<<<dim3( 6, 5), 256, 0, stream>>>(Wv,     342,  384, WvT);
    k_trw<<<dim3(16, 5), 256, 0, stream>>>(Wt_in, 1024, 1024, WtT);

    k_projg2<<<dim3(5, 7, 4), 256, 0, stream>>>(xga, 1600, 400, WaT, xpa);
    k_projg2<<<dim3(5, 7, 2), 256, 0, stream>>>(xgv,  384, 192, WvT, xpv);
    k_projg2<<<dim3(5, 7, 4), 256, 0, stream>>>(xgt, 1024, 256, WtT, xpt);

    k_norm2<<<M3, 256, 0, stream>>>(xpa, xpv, xpt, ba, bv, bt, spk_emb, spki, rmap3, x, fn, N);

    int nt = (N + 31)/32;
    k_intra<<<dim3(nt, nt, 3), dim3(16,16), 0, stream>>>(fn, dia, rmap3, A, N);
    k_cross<<<N, 64, 0, stream>>>(fn, rmap3, A, N);
    k_rowsum<<<M3, 256, 0, stream>>>(A, dinv, M3);
    k_scale<<<dim3(78, 78), dim3(16,16), 0, stream>>>(A, Abf, dinv, M3);

    k_gemm_h0<<<dim3(8, 20), 256, 0, stream>>>(x, W_in, b_in, h0, h0b, h0bT, M3);
    k_wtr<<<dim3(16, 8, 64), 256, 0, stream>>>(W_convs, Wt);

    const us* srcp = h0bT;
    for (int l = 1; l <= 64; ++l){
        us* dstp = ((l-1) & 1) ? hTb : hTa;
        float thv = logf(0.5f/(float)l + 1.0f);
        k_spmm<<<dim3(8, 20), 256, 0, stream>>>(Abf, srcp, tileK, hi, hib);
        k_layerm<<<dim3(8, 20), 256, 0, stream>>>(hib, h0b, Wt + (size_t)(l-1)*LDH*1024,
                                                  hi, h0, thv, 1.0f - thv, dstp);
        srcp = dstp;
    }

    k_final<<<N, 64, 0, stream>>>(hTb, W_fc1, b_fc1, rmap3, (float*)d_out, N);
}

// Round 11
// 1746.440 us; speedup vs baseline: 1.6390x; 1.0864x over previous
//
#include <hip/hip_runtime.h>
#include <hip/hip_bf16.h>
#include <math.h>

#define LDAB 1344  // A_perm col stride (1233 -> 1344)
#define LDR  1344  // hT row capacity
#define LDH  512   // padded G (500 -> 512)
#define LDX  320   // padded H (300 -> 320)

typedef __attribute__((ext_vector_type(8))) short short8;
typedef __attribute__((ext_vector_type(4))) float f32x4;
typedef unsigned short us;

__device__ __forceinline__ us f2b(float x){
    unsigned int u = __float_as_uint(x);
    return (us)((u + 0x7fffu + ((u >> 16) & 1u)) >> 16);
}
__device__ __forceinline__ float b2f(us u){ return __uint_as_float(((unsigned int)u) << 16); }

__device__ __forceinline__ float arc_sim(float c){
    float cc = fminf(1.f, fmaxf(-1.f, c * 0.99999f));
    return 1.f - acosf(cc) * 0.31830988618379067f;
}

#define SWZ(r, k)    (((r)*64  + (k)) ^ (((r)&7)<<3))
#define SWZ256(r, k) ((r)*256 + ((k) ^ (((r)&7)<<3)))

// ---------------- offsets / permutation map / tile bands (PARALLEL) ----------------
__global__ __launch_bounds__(256)
void k_offsets(const int* __restrict__ dia, int N,
               int* __restrict__ off13, int* __restrict__ rmap3, int* __restrict__ tileK)
{
    __shared__ int soff[13], slen[12];
    int t = threadIdx.x;
    if (t <= 12) soff[t] = (t == 0) ? 0 : N;
    __syncthreads();
    for (int i = t + 1; i < N; i += 256){
        int d = dia[i];
        if (dia[i-1] != d) soff[d] = i;      // unique writer per dialogue id
    }
    __syncthreads();
    if (t == 0){
        for (int d = 11; d >= 1; --d) soff[d] = min(soff[d], soff[d+1]);
    }
    __syncthreads();
    if (t < 12) slen[t] = soff[t+1] - soff[t];
    if (t < 13) off13[t] = soff[t];
    __syncthreads();
    for (int i = t; i < N; i += 256){
        int d = dia[i];
        int base = 3*soff[d], u = i - soff[d], l = slen[d];
        rmap3[0*448 + i] = base + u;
        rmap3[1*448 + i] = base + l + u;
        rmap3[2*448 + i] = base + 2*l + u;
    }
    if (t < 20){
        int it = t;
        int r0 = it*64, r1 = min(it*64 + 63, 3*N - 1);
        int dfirst = 11, dlast = 11;
        for (int dd = 0; dd < 12; ++dd){ if (r0 < 3*soff[dd+1]){ dfirst = dd; break; } }
        for (int dd = 0; dd < 12; ++dd){ if (r1 < 3*soff[dd+1]){ dlast = dd; break; } }
        tileK[it]      = (3*soff[dfirst]) & ~63;       // 64-aligned band start
        tileK[20 + it] = 3*soff[dlast] + 3*slen[dlast];
    }
}

// ---------------- gather ragged utterances into padded buffers + speaker idx ----------------
__global__ __launch_bounds__(256)
void k_gather(const float* __restrict__ fa, const float* __restrict__ fv, const float* __restrict__ ft,
              const float* __restrict__ speaker, const int* __restrict__ seq, const int* __restrict__ bat,
              float* __restrict__ xga, float* __restrict__ xgv, float* __restrict__ xgt,
              int* __restrict__ spki, int N)
{
    int i = blockIdx.x;
    int tid = threadIdx.x;
    bool real = i < N;
    int s = real ? seq[i] : 0, b = real ? bat[i] : 0;
    size_t base = (size_t)(s*12 + b);
    for (int k = tid; k < 1600; k += 256) xga[(size_t)i*1600 + k] = (real && k < 1582) ? fa[base*1582 + k] : 0.f;
    for (int k = tid; k < 384;  k += 256) xgv[(size_t)i*384  + k] = (real && k < 342)  ? fv[base*342  + k] : 0.f;
    for (int k = tid; k < 1024; k += 256) xgt[(size_t)i*1024 + k] = real ? ft[base*1024 + k] : 0.f;
    if (tid == 0){
        int bi = 0;
        if (real){
            const float* sp = speaker + base*9;
            float best = sp[0];
            for (int c = 1; c < 9; ++c) if (sp[c] > best){ best = sp[c]; bi = c; }
        }
        spki[i] = bi;
    }
}

// ---------------- transpose projection weight W[D][300] -> WT[300][Kp] fp32 ----------------
__global__ __launch_bounds__(256)
void k_trw(const float* __restrict__ W, int D, int Kp, float* __restrict__ WTr)
{
    __shared__ float tt[64][65];
    int k0 = blockIdx.x*64, j0 = blockIdx.y*64;
    int t = threadIdx.x;
    #pragma unroll
    for (int rr = 0; rr < 4; ++rr){
        int kl = (t >> 4) + rr*16;
        int k  = k0 + kl;
        int jl = (t & 15) * 4;
        int j  = j0 + jl;
        float4 v;
        if (k < D && j + 3 < 300){
            v = *(const float4*)&W[(size_t)k*300 + j];
        } else {
            v.x = (k < D && j+0 < 300) ? W[(size_t)k*300 + j+0] : 0.f;
            v.y = (k < D && j+1 < 300) ? W[(size_t)k*300 + j+1] : 0.f;
            v.z = (k < D && j+2 < 300) ? W[(size_t)k*300 + j+2] : 0.f;
            v.w = (k < D && j+3 < 300) ? W[(size_t)k*300 + j+3] : 0.f;
        }
        tt[jl+0][kl] = v.x; tt[jl+1][kl] = v.y; tt[jl+2][kl] = v.z; tt[jl+3][kl] = v.w;
    }
    __syncthreads();
    #pragma unroll
    for (int rr = 0; rr < 4; ++rr){
        int jl = (t >> 4) + rr*16;
        int j  = j0 + jl;
        int kq = (t & 15) * 4;
        if (j < 300){
            float4 o; o.x = tt[jl][kq]; o.y = tt[jl][kq+1]; o.z = tt[jl][kq+2]; o.w = tt[jl][kq+3];
            *(float4*)&WTr[(size_t)j*Kp + k0 + kq] = o;
        }
    }
}

// ---------------- projection GEMM partials (split-K) ----------------
__global__ __launch_bounds__(256)
void k_projg2(const float* __restrict__ xg, int Kp, int kslice,
              const float* __restrict__ WTr, float* __restrict__ xp)
{
    __shared__ float As[16][68];
    __shared__ float Bs[16][64];
    int i0 = blockIdx.y*64, j0 = blockIdx.x*64;
    int ks0 = blockIdx.z * kslice;
    int tid = threadIdx.x;
    int ty = tid >> 4, tx = tid & 15;
    int lr = tid >> 2, lk = (tid & 3) << 2;
    int bj = tid & 63, bk4 = (tid >> 6) << 2;
    float acc[4][4] = {};
    for (int k0 = 0; k0 < kslice; k0 += 16){
        float4 av = *(const float4*)&xg[(size_t)(i0+lr)*Kp + ks0 + k0 + lk];
        float4 wv = {0.f, 0.f, 0.f, 0.f};
        int j = j0 + bj;
        if (j < 300) wv = *(const float4*)&WTr[(size_t)j*Kp + ks0 + k0 + bk4];
        __syncthreads();
        As[lk+0][lr] = av.x; As[lk+1][lr] = av.y; As[lk+2][lr] = av.z; As[lk+3][lr] = av.w;
        Bs[bk4+0][bj] = wv.x; Bs[bk4+1][bj] = wv.y; Bs[bk4+2][bj] = wv.z; Bs[bk4+3][bj] = wv.w;
        __syncthreads();
        #pragma unroll
        for (int kk = 0; kk < 16; ++kk){
            float4 a4 = *(const float4*)&As[kk][ty*4];
            float4 b4 = *(const float4*)&Bs[kk][tx*4];
            float a_[4] = {a4.x, a4.y, a4.z, a4.w};
            float b_[4] = {b4.x, b4.y, b4.z, b4.w};
            #pragma unroll
            for (int u = 0; u < 4; ++u)
                #pragma unroll
                for (int v = 0; v < 4; ++v) acc[u][v] += a_[u]*b_[v];
        }
    }
    #pragma unroll
    for (int u = 0; u < 4; ++u){
        int i = i0 + ty*4 + u;
        #pragma unroll
        for (int v = 0; v < 4; ++v)
            xp[((size_t)blockIdx.z*448 + i)*320 + j0 + tx*4 + v] = acc[u][v];
    }
}

// ---------------- reduce split-K + bias + spk -> x (PERMUTED rows) and fn ----------------
__global__ __launch_bounds__(256)
void k_norm2(const float* __restrict__ xpa, const float* __restrict__ xpv, const float* __restrict__ xpt,
             const float* __restrict__ ba, const float* __restrict__ bv, const float* __restrict__ bt,
             const float* __restrict__ spk_emb, const int* __restrict__ spki,
             const int* __restrict__ rmap3,
             float* __restrict__ x, float* __restrict__ fn, int N)
{
    __shared__ float red[4];
    int r = blockIdx.x, tid = threadIdx.x;
    int m = (r >= 2*N) ? 2 : (r >= N ? 1 : 0);
    int n = r - m*N;
    const float* xp   = (m==0) ? xpa : (m==1) ? xpv : xpt;
    const float* bias = (m==0) ? ba  : (m==1) ? bv  : bt;
    int KS = (m==1) ? 2 : 4;
    float v0 = 0.f, v1 = 0.f;
    int j0 = tid, j1 = tid + 256;
    if (j0 < 300){
        float s = bias[j0];
        for (int si = 0; si < KS; ++si) s += xp[((size_t)si*448 + n)*320 + j0];
        if (m == 2) s += spk_emb[spki[n]*300 + j0];
        v0 = s;
    }
    if (j1 < 300){
        float s = bias[j1];
        for (int si = 0; si < KS; ++si) s += xp[((size_t)si*448 + n)*320 + j1];
        if (m == 2) s += spk_emb[spki[n]*300 + j1];
        v1 = s;
    }
    float ss = v0*v0 + v1*v1;
    #pragma unroll
    for (int off = 32; off > 0; off >>= 1) ss += __shfl_down(ss, off, 64);
    if ((tid & 63) == 0) red[tid >> 6] = ss;
    __syncthreads();
    float tot = red[0] + red[1] + red[2] + red[3];
    float inv = 1.f / (sqrtf(tot) + 1e-8f);
    int prow = rmap3[m*448 + n];
    x [(size_t)prow*LDX + j0] = v0;
    fn[(size_t)r*LDX + j0] = v0 * inv;
    if (j1 < 320){
        x [(size_t)prow*LDX + j1] = v1;
        fn[(size_t)r*LDX + j1] = v1 * inv;
    }
}

// ---------------- intra-modal adjacency -> PERMUTED block-diagonal A ----------------
__global__ __launch_bounds__(256)
void k_intra(const float* __restrict__ fn, const int* __restrict__ dia,
             const int* __restrict__ rmap3, float* __restrict__ A, int N)
{
    int m  = blockIdx.z;
    int i0 = blockIdx.y * 32, j0 = blockIdx.x * 32;
    int iend = min(i0 + 31, N - 1), jend = min(j0 + 31, N - 1);
    if (dia[iend] < dia[j0] || dia[jend] < dia[i0]) return;

    __shared__ float As[32][17], Bs[32][17];
    int tx = threadIdx.x, ty = threadIdx.y;
    int tid = ty*16 + tx;
    float acc[2][2] = {};
    for (int k0 = 0; k0 < 320; k0 += 16){
        __syncthreads();
        for (int l = tid; l < 512; l += 256){
            int r = l >> 4, kk = l & 15;
            int gi = i0 + r, gj = j0 + r;
            As[r][kk] = (gi < N) ? fn[((size_t)m*N + gi)*LDX + k0 + kk] : 0.f;
            Bs[r][kk] = (gj < N) ? fn[((size_t)m*N + gj)*LDX + k0 + kk] : 0.f;
        }
        __syncthreads();
        #pragma unroll
        for (int kk = 0; kk < 16; ++kk){
            float a0 = As[ty*2+0][kk], a1 = As[ty*2+1][kk];
            float b0 = Bs[tx*2+0][kk], b1 = Bs[tx*2+1][kk];
            acc[0][0] += a0*b0; acc[0][1] += a0*b1;
            acc[1][0] += a1*b0; acc[1][1] += a1*b1;
        }
    }
    #pragma unroll
    for (int u = 0; u < 2; ++u)
        #pragma unroll
        for (int v = 0; v < 2; ++v){
            int i = i0 + ty*2 + u, j = j0 + tx*2 + v;
            if (i < N && j < N && dia[i] == dia[j]){
                int pi = rmap3[m*448 + i], pj = rmap3[m*448 + j];
                A[(size_t)pi*LDAB + pj] = arc_sim(acc[u][v]);
            }
        }
}

// ---------------- cross-modal diagonal links (permuted) ----------------
__global__ void k_cross(const float* __restrict__ fn, const int* __restrict__ rmap3,
                        float* __restrict__ A, int N)
{
    int i = blockIdx.x, lane = threadIdx.x;
    float d01 = 0.f, d02 = 0.f, d12 = 0.f;
    for (int k = lane; k < 300; k += 64){
        float a = fn[((size_t)0*N + i)*LDX + k];
        float b = fn[((size_t)1*N + i)*LDX + k];
        float c = fn[((size_t)2*N + i)*LDX + k];
        d01 += a*b; d02 += a*c; d12 += b*c;
    }
    #pragma unroll
    for (int off = 32; off > 0; off >>= 1){
        d01 += __shfl_down(d01, off, 64);
        d02 += __shfl_down(d02, off, 64);
        d12 += __shfl_down(d12, off, 64);
    }
    if (lane == 0){
        float s01 = arc_sim(d01), s02 = arc_sim(d02), s12 = arc_sim(d12);
        size_t p0 = rmap3[i], p1 = rmap3[448 + i], p2 = rmap3[896 + i];
        A[p0*LDAB + p1] = s01; A[p1*LDAB + p0] = s01;
        A[p0*LDAB + p2] = s02; A[p2*LDAB + p0] = s02;
        A[p1*LDAB + p2] = s12; A[p2*LDAB + p1] = s12;
    }
}

// ---------------- degree + D^-1/2 ----------------
__global__ __launch_bounds__(256)
void k_rowsum(const float* __restrict__ A, float* __restrict__ dinv, int M3)
{
    __shared__ float red[4];
    int r = blockIdx.x, tid = threadIdx.x;
    float s = 0.f;
    for (int c = tid; c < LDAB; c += 256) s += A[(size_t)r*LDAB + c];
    #pragma unroll
    for (int off = 32; off > 0; off >>= 1) s += __shfl_down(s, off, 64);
    if ((tid & 63) == 0) red[tid >> 6] = s;
    __syncthreads();
    if (tid == 0){
        float tot = red[0] + red[1] + red[2] + red[3];
        dinv[r] = (tot > 0.f) ? 1.f / sqrtf(tot) : 0.f;
    }
}

// ---------------- scale + bf16 copy ----------------
__global__ void k_scale(float* __restrict__ A, us* __restrict__ Abf,
                        const float* __restrict__ dinv, int M3)
{
    int c = blockIdx.x*16 + threadIdx.x;
    int r = blockIdx.y*16 + threadIdx.y;
    if (r < M3 && c < M3){
        float v = A[(size_t)r*LDAB + c] * dinv[r]*dinv[c];
        A[(size_t)r*LDAB + c] = v;
        Abf[(size_t)r*LDAB + c] = f2b(v);
    }
}

// ---------------- h0 = relu(x @ W_in + b_in) (permuted rows) ----------------
__global__ __launch_bounds__(256)
void k_gemm_h0(const float* __restrict__ x, const float* __restrict__ Win,
               const float* __restrict__ bin, float* __restrict__ h0,
               us* __restrict__ h0b, us* __restrict__ h0bT, int M3)
{
    __shared__ float As[16][68];
    __shared__ float Bs[16][64];
    int i0 = blockIdx.y*64, j0 = blockIdx.x*64;
    int tid = threadIdx.x;
    int ty = tid >> 4, tx = tid & 15;
    int lr = tid >> 2, lk = (tid & 3) << 2;
    int br = tid >> 4, bc = (tid & 15) << 2;
    float acc[4][4] = {};
    for (int k0 = 0; k0 < 320; k0 += 16){
        float4 av = *(const float4*)&x[(size_t)(i0+lr)*LDX + k0 + lk];
        float4 bwv;
        {
            int kr = k0 + br;
            int c0 = j0 + bc;
            if (kr < 300 && c0 + 3 < 500){
                bwv = *(const float4*)&Win[(size_t)kr*500 + c0];
            } else {
                bwv.x = (kr < 300 && c0+0 < 500) ? Win[(size_t)kr*500 + c0+0] : 0.f;
                bwv.y = (kr < 300 && c0+1 < 500) ? Win[(size_t)kr*500 + c0+1] : 0.f;
                bwv.z = (kr < 300 && c0+2 < 500) ? Win[(size_t)kr*500 + c0+2] : 0.f;
                bwv.w = (kr < 300 && c0+3 < 500) ? Win[(size_t)kr*500 + c0+3] : 0.f;
            }
        }
        __syncthreads();
        As[lk+0][lr] = av.x; As[lk+1][lr] = av.y; As[lk+2][lr] = av.z; As[lk+3][lr] = av.w;
        *(float4*)&Bs[br][bc] = bwv;
        __syncthreads();
        #pragma unroll
        for (int kk = 0; kk < 16; ++kk){
            float4 a4 = *(const float4*)&As[kk][ty*4];
            float4 b4 = *(const float4*)&Bs[kk][tx*4];
            float a_[4] = {a4.x, a4.y, a4.z, a4.w};
            float b_[4] = {b4.x, b4.y, b4.z, b4.w};
            #pragma unroll
            for (int u = 0; u < 4; ++u)
                #pragma unroll
                for (int v = 0; v < 4; ++v) acc[u][v] += a_[u]*b_[v];
        }
    }
    #pragma unroll
    for (int u = 0; u < 4; ++u){
        int i = i0 + ty*4 + u;
        #pragma unroll
        for (int v = 0; v < 4; ++v){
            int j = j0 + tx*4 + v;
            float val = 0.f;
            if (i < M3 && j < 500) val = fmaxf(acc[u][v] + bin[j], 0.f);
            h0[(size_t)i*LDH + j] = val;
            us bv = f2b(val);
            h0b[(size_t)i*LDH + j] = bv;
            h0bT[(size_t)j*LDR + i] = bv;
        }
    }
}

// ---------------- convert ALL 64 layers of W to bf16 transposed ----------------
__global__ __launch_bounds__(256)
void k_wtr(const float* __restrict__ Wc, us* __restrict__ Wt)
{
    __shared__ us sT[64][72];
    int l = blockIdx.z;
    int k0 = blockIdx.x*64, j0 = blockIdx.y*64;
    const float* W = Wc + (size_t)l*500000;
    int ksrc0 = (k0 < 512) ? k0 : k0 - 12;
    int klim  = (k0 < 512) ? 500 : 1000;
    int t = threadIdx.x;
    #pragma unroll
    for (int rr = 0; rr < 4; ++rr){
        int kl = (t >> 4) + rr*16;
        int k  = ksrc0 + kl;
        int jl = (t & 15) * 4;
        int j  = j0 + jl;
        bool vk = (k < klim);
        float4 v;
        if (vk && j + 3 < 500){
            v = *(const float4*)&W[(size_t)k*500 + j];
        } else {
            v.x = (vk && j+0 < 500) ? W[(size_t)k*500 + j+0] : 0.f;
            v.y = (vk && j+1 < 500) ? W[(size_t)k*500 + j+1] : 0.f;
            v.z = (vk && j+2 < 500) ? W[(size_t)k*500 + j+2] : 0.f;
            v.w = (vk && j+3 < 500) ? W[(size_t)k*500 + j+3] : 0.f;
        }
        sT[jl+0][kl] = f2b(v.x);
        sT[jl+1][kl] = f2b(v.y);
        sT[jl+2][kl] = f2b(v.z);
        sT[jl+3][kl] = f2b(v.w);
    }
    __syncthreads();
    int jl = t >> 2, kc = (t & 3) * 16;
    us* dst = Wt + (size_t)l*LDH*1024 + (size_t)(j0+jl)*1024 + k0 + kc;
    *(uint4*)&dst[0] = *(const uint4*)&sT[jl][kc];
    *(uint4*)&dst[8] = *(const uint4*)&sT[jl][kc+8];
}

// ---------------- fused per-layer kernel (256 thr = 4 waves, grid 160 = 20 it x 8 jt) --------
// Phase 1: hi slab[64][512] = A[i-band] @ h  (banded K, staged LDS, stays in LDS)
// Phase 2: out[64][64] = [slab | h0b] @ W  (BK=256 staged), GCNII epilogue from fp32 window
__global__ __launch_bounds__(256)
void k_fuse(const us* __restrict__ Abf, const us* __restrict__ src,
            const float* __restrict__ h0, const us* __restrict__ h0b,
            const us* __restrict__ Wl, const int* __restrict__ tileK,
            float th, us* __restrict__ dst)
{
    __shared__ __align__(16) char smem[148480];
    us*    sH   = (us*)smem;                    // phase1 staging [512 cols][64 k] swz   (64KB)
    us*    slab = (us*)smem;                    // phase1 output  [64 rows][512] swz-row (64KB, aliases sH)
    float* sepF = (float*)(smem + 65536);       // fp32 hi window [64][68]               (17.4KB)
    us*    sA   = (us*)(smem + 82944);          // phase1 A tile  [64][64] swz           (8KB)
    us*    sB   = (us*)(smem + 82944);          // phase2 W tile  [64][256] swz256       (32KB, aliases sA)
    us*    sH0  = (us*)(smem + 115712);         // phase2 h0 tile [64][256] swz256       (32KB)

    const int tid = threadIdx.x, lane = tid & 63, w = tid >> 6;
    const int lm = lane & 15, lq = lane >> 4;
    const int it = blockIdx.x >> 3, jt = blockIdx.x & 7;
    const int i0 = it*64, j0 = jt*64;
    const int kminf = tileK[it];
    const int kmax  = tileK[20 + it];
    const int T = (kmax - kminf + 63) >> 6;
    const int arow = tid >> 2, ac8 = (tid & 3) * 16;

    // ===== phase 1: banded GEMM1 =====
    f32x4 accS[4][8] = {};
    for (int t = 0; t < T; ++t){
        int kb = kminf + t*64;
        __syncthreads();
        {   // A tile 64x64 (2 x uint4 / thread)
            const us* pa = &Abf[(size_t)(i0+arow)*LDAB + kb + ac8];
            *(uint4*)&sA[SWZ(arow, ac8)]     = *(const uint4*)(pa);
            *(uint4*)&sA[SWZ(arow, ac8 + 8)] = *(const uint4*)(pa + 8);
        }
        #pragma unroll
        for (int q = 0; q < 16; ++q){   // H tile 512x64 (16 x uint4 / thread)
            int c = tid + 256*q;
            int r = c >> 3, k8 = (c & 7) * 8;
            *(uint4*)&sH[SWZ(r, k8)] = *(const uint4*)&src[(size_t)r*LDR + kb + k8];
        }
        __syncthreads();
        #pragma unroll
        for (int ks = 0; ks < 2; ++ks){
            int kk = ks*32 + lq*8;
            short8 af[4], bf[8];
            #pragma unroll
            for (int fr = 0; fr < 4; ++fr) af[fr] = *(const short8*)&sA[SWZ(fr*16 + lm, kk)];
            #pragma unroll
            for (int fc = 0; fc < 8; ++fc) bf[fc] = *(const short8*)&sH[SWZ(w*128 + fc*16 + lm, kk)];
            #pragma unroll
            for (int fr = 0; fr < 4; ++fr)
                #pragma unroll
                for (int fc = 0; fc < 8; ++fc)
                    accS[fr][fc] = __builtin_amdgcn_mfma_f32_16x16x32_bf16(af[fr], bf[fc], accS[fr][fc], 0, 0, 0);
        }
    }
    __syncthreads();   // sH dead -> region becomes slab

    // write slab (bf16, row-swizzled) + fp32 window for this block's jt column
    #pragma unroll
    for (int fr = 0; fr < 4; ++fr)
        #pragma unroll
        for (int fc = 0; fc < 8; ++fc)
            #pragma unroll
            for (int rg = 0; rg < 4; ++rg){
                int row = fr*16 + lq*4 + rg;
                int col = w*128 + fc*16 + lm;
                float v = accS[fr][fc][rg];
                slab[row*512 + (col ^ ((row&7)<<3))] = f2b(v);
                if ((col >> 6) == jt) sepF[row*68 + (col & 63)] = v;
            }
    __syncthreads();

    // ===== phase 2: GEMM2, out 64x64, K=1024 = [slab(512) | h0b(512)], BK=256 =====
    const int wr = w >> 1, wc = w & 1;
    f32x4 accG[2][2] = {};
    for (int s = 0; s < 4; ++s){
        __syncthreads();
        #pragma unroll
        for (int q = 0; q < 8; ++q){    // W tile 64x256 (8 x uint4 / thread)
            int c = tid + 256*q, r = c >> 5, k8 = (c & 31) * 8;
            *(uint4*)&sB[SWZ256(r, k8)] = *(const uint4*)&Wl[(size_t)(j0+r)*1024 + s*256 + k8];
        }
        if (s >= 2){
            #pragma unroll
            for (int q = 0; q < 8; ++q){ // h0 tile 64x256
                int c = tid + 256*q, r = c >> 5, k8 = (c & 31) * 8;
                *(uint4*)&sH0[SWZ256(r, k8)] = *(const uint4*)&h0b[(size_t)(i0+r)*LDH + (s*256 - 512) + k8];
            }
        }
        __syncthreads();
        #pragma unroll
        for (int ks = 0; ks < 8; ++ks){
            int kk = ks*32 + lq*8;
            short8 a0, a1, b0, b1;
            if (s < 2){
                int r0 = wr*32 + lm, r1 = wr*32 + 16 + lm;
                int kp = s*256 + kk;
                a0 = *(const short8*)&slab[r0*512 + (kp ^ ((r0&7)<<3))];
                a1 = *(const short8*)&slab[r1*512 + (kp ^ ((r1&7)<<3))];
            } else {
                a0 = *(const short8*)&sH0[SWZ256(wr*32 + lm, kk)];
                a1 = *(const short8*)&sH0[SWZ256(wr*32 + 16 + lm, kk)];
            }
            b0 = *(const short8*)&sB[SWZ256(wc*32 + lm, kk)];
            b1 = *(const short8*)&sB[SWZ256(wc*32 + 16 + lm, kk)];
            accG[0][0] = __builtin_amdgcn_mfma_f32_16x16x32_bf16(a0, b0, accG[0][0], 0, 0, 0);
            accG[0][1] = __builtin_amdgcn_mfma_f32_16x16x32_bf16(a0, b1, accG[0][1], 0, 0, 0);
            accG[1][0] = __builtin_amdgcn_mfma_f32_16x16x32_bf16(a1, b0, accG[1][0], 0, 0, 0);
            accG[1][1] = __builtin_amdgcn_mfma_f32_16x16x32_bf16(a1, b1, accG[1][1], 0, 0, 0);
        }
    }

    // ===== epilogue: h_next = relu(th*G2 + (1-th)*(0.9*hi + 0.1*h0)), write transposed =====
    float cth = 1.f - th;
    #pragma unroll
    for (int fr = 0; fr < 2; ++fr)
        #pragma unroll
        for (int fc = 0; fc < 2; ++fc){
            unsigned int pk[2];
            unsigned int t0 = 0, t1 = 0;
            #pragma unroll
            for (int rg = 0; rg < 4; ++rg){
                int il = wr*32 + fr*16 + lq*4 + rg;
                int jl = wc*32 + fc*16 + lm;
                float hiv = sepF[il*68 + jl];
                float h0v = h0[(size_t)(i0 + il)*LDH + j0 + jl];
                float o = fmaxf(th*accG[fr][fc][rg] + cth*(0.9f*hiv + 0.1f*h0v), 0.f);
                unsigned int ob = (unsigned int)f2b(o);
                if (rg < 2) t0 |= ob << (16*rg);
                else        t1 |= ob << (16*(rg-2));
            }
            pk[0] = t0; pk[1] = t1;
            int jg = j0 + wc*32 + fc*16 + lm;
            int ig = i0 + wr*32 + fr*16 + lq*4;
            *(uint2*)&dst[(size_t)jg*LDR + ig] = *(uint2*)pk;
        }
}

// ---------------- final classify + log_softmax ----------------
__global__ void k_final(const us* __restrict__ hT, const float* __restrict__ Wfc,
                        const float* __restrict__ bfc, const int* __restrict__ rmap3,
                        float* __restrict__ out, int N)
{
    int i = blockIdx.x, lane = threadIdx.x;
    int p0 = rmap3[i], p1 = rmap3[448 + i], p2 = rmap3[896 + i];
    float acc[7] = {};
    for (int k = lane; k < 1500; k += 64){
        int m = (k >= 1000) ? 2 : ((k >= 500) ? 1 : 0);
        int kk = k - m*500;
        int prow = (m == 0) ? p0 : (m == 1) ? p1 : p2;
        float f = fmaxf(b2f(hT[(size_t)kk*LDR + prow]), 0.f);
        #pragma unroll
        for (int c = 0; c < 7; ++c) acc[c] += f * Wfc[(size_t)k*7 + c];
    }
    #pragma unroll
    for (int off = 32; off > 0; off >>= 1){
        #pragma unroll
        for (int c = 0; c < 7; ++c) acc[c] += __shfl_down(acc[c], off, 64);
    }
    if (lane == 0){
        float lg[7], mx = -1e30f;
        #pragma unroll
        for (int c = 0; c < 7; ++c){ lg[c] = acc[c] + bfc[c]; mx = fmaxf(mx, lg[c]); }
        float s = 0.f;
        #pragma unroll
        for (int c = 0; c < 7; ++c) s += expf(lg[c] - mx);
        float lse = mx + logf(s);
        #pragma unroll
        for (int c = 0; c < 7; ++c) out[(size_t)i*7 + c] = lg[c] - lse;
    }
}

extern "C" void kernel_launch(void* const* d_in, const int* in_sizes, int n_in,
                              void* d_out, int out_size, void* d_ws, size_t ws_size,
                              hipStream_t stream)
{
    const float* speaker = (const float*)d_in[1];
    const float* fea_a   = (const float*)d_in[2];
    const float* fea_v   = (const float*)d_in[3];
    const float* fea_t   = (const float*)d_in[4];
    const float* Wa      = (const float*)d_in[5];
    const float* ba      = (const float*)d_in[6];
    const float* Wv      = (const float*)d_in[7];
    const float* bv      = (const float*)d_in[8];
    const float* Wt_in   = (const float*)d_in[9];
    const float* bt      = (const float*)d_in[10];
    const float* spk_emb = (const float*)d_in[11];
    const float* W_in    = (const float*)d_in[12];
    const float* b_in    = (const float*)d_in[13];
    const float* W_convs = (const float*)d_in[14];
    const float* W_fc1   = (const float*)d_in[15];
    const float* b_fc1   = (const float*)d_in[16];
    const int* seq = (const int*)d_in[18];
    const int* bat = (const int*)d_in[19];
    const int* dia = (const int*)d_in[20];

    const int N  = in_sizes[18];   // 411
    const int M3 = 3*N;            // 1233

    char* wsb = (char*)d_ws;
    float* A     = (float*)(wsb + 0);             // 1344*1344*4 = 7,225,344
    us*    Abf   = (us*)   (wsb + 8388608);       // 3,612,672
    float* x     = (float*)(wsb + 12582912);
    float* fn    = (float*)(wsb + 14680064);
    float* h0    = (float*)(wsb + 16777216);
    us*    h0b   = (us*)   (wsb + 19922944);
    us*    h0bT  = (us*)   (wsb + 21495808);      // 512*1344*2
    us*    hTa   = (us*)   (wsb + 23068672);
    us*    hTb   = (us*)   (wsb + 24641536);
    us*    Wt    = (us*)   (wsb + 33554432);      // 64*512*1024*2 = 67,108,864
    float* dinv  = (float*)(wsb + 100663296);
    int*   off13 = (int*)  (wsb + 100669440);
    int*   rmap3 = (int*)  (wsb + 100670464);
    int*   tileK = (int*)  (wsb + 100676608);
    int*   spki  = (int*)  (wsb + 100853760);
    float* xga   = (float*)(wsb + 100859904);
    float* xgv   = (float*)(wsb + 103727104);
    float* xgt   = (float*)(wsb + 104415232);
    float* WaT   = (float*)(wsb + 106250240);
    float* WvT   = (float*)(wsb + 108170240);
    float* WtT   = (float*)(wsb + 108631040);
    float* xpa   = (float*)(wsb + 109859840);
    float* xpv   = (float*)(wsb + 112153600);
    float* xpt   = (float*)(wsb + 113300480);

    hipMemsetAsync(A,    0, 7225344, stream);
    hipMemsetAsync(Abf,  0, 3612672, stream);
    hipMemsetAsync(x,    0, 1638400, stream);
    hipMemsetAsync(fn,   0, 1638400, stream);
    hipMemsetAsync(h0bT, 0, 1376256, stream);
    hipMemsetAsync(hTa,  0, 1376256, stream);
    hipMemsetAsync(hTb,  0, 1376256, stream);

    k_offsets<<<1, 256, 0, stream>>>(dia, N, off13, rmap3, tileK);
    k_gather<<<448, 256, 0, stream>>>(fea_a, fea_v, fea_t, speaker, seq, bat, xga, xgv, xgt, spki, N);

    k_trw<<<dim3(25, 5), 256, 0, stream>>>(Wa,    1582, 1600, WaT);
    k_trw<<<dim3( 6, 5), 256, 0, stream>>>(Wv,     342,  384, WvT);
    k_trw<<<dim3(16, 5), 256, 0, stream>>>(Wt_in, 1024, 1024, WtT);

    k_projg2<<<dim3(5, 7, 4), 256, 0, stream>>>(xga, 1600, 400, WaT, xpa);
    k_projg2<<<dim3(5, 7, 2), 256, 0, stream>>>(xgv,  384, 192, WvT, xpv);
    k_projg2<<<dim3(5, 7, 4), 256, 0, stream>>>(xgt, 1024, 256, WtT, xpt);

    k_norm2<<<M3, 256, 0, stream>>>(xpa, xpv, xpt, ba, bv, bt, spk_emb, spki, rmap3, x, fn, N);

    int nt = (N + 31)/32;
    k_intra<<<dim3(nt, nt, 3), dim3(16,16), 0, stream>>>(fn, dia, rmap3, A, N);
    k_cross<<<N, 64, 0, stream>>>(fn, rmap3, A, N);
    k_rowsum<<<M3, 256, 0, stream>>>(A, dinv, M3);
    k_scale<<<dim3(78, 78), dim3(16,16), 0, stream>>>(A, Abf, dinv, M3);

    k_gemm_h0<<<dim3(8, 20), 256, 0, stream>>>(x, W_in, b_in, h0, h0b, h0bT, M3);
    k_wtr<<<dim3(16, 8, 64), 256, 0, stream>>>(W_convs, Wt);

    const us* srcp = h0bT;
    for (int l = 1; l <= 64; ++l){
        us* dstp = ((l-1) & 1) ? hTb : hTa;
        float thv = logf(0.5f/(float)l + 1.0f);
        k_fuse<<<160, 256, 0, stream>>>(Abf, srcp, h0, h0b,
                                        Wt + (size_t)(l-1)*LDH*1024, tileK, thv, dstp);
        srcp = dstp;
    }

    k_final<<<N, 64, 0, stream>>>(hTb, W_fc1, b_fc1, rmap3, (float*)d_out, N);
}